// Round 2
// baseline (716.556 us; speedup 1.0000x reference)
//
#include <hip/hip_runtime.h>

#define NTOK 512
#define CS 384
#define CZ 128
#define CH 16
#define HN 12
#define PQ 4
#define PV 8
#define FEAT_DIM 2112   // HN * 176
#define HSEG 176        // 16 + 24 + 8 + 128

// ---------------------------------------------------------------------------
// K1: projections q,k,v (scalar) and q_pts,k_pts,v_pts -> global frame
// block = 256 threads, handles 4 tokens (amortize weight reads)
// ---------------------------------------------------------------------------
__global__ __launch_bounds__(256) void k_proj(
    const float* __restrict__ s,
    const float* __restrict__ trans,
    const float* __restrict__ rot,
    const float* __restrict__ Wq,  const float* __restrict__ bq,
    const float* __restrict__ Wk,  const float* __restrict__ bk,
    const float* __restrict__ Wv,  const float* __restrict__ bv,
    const float* __restrict__ Wqp, const float* __restrict__ bqp,
    const float* __restrict__ Wkp, const float* __restrict__ bkp,
    const float* __restrict__ Wvp, const float* __restrict__ bvp,
    float* __restrict__ qs, float* __restrict__ ks, float* __restrict__ vs,
    float* __restrict__ qg, float* __restrict__ kg, float* __restrict__ vg)
{
    __shared__ float s_l[4][CS];
    __shared__ float raw[4][576];   // qp[0:144) kp[144:288) vp[288:576)
    __shared__ float Rl[4][9];
    __shared__ float tl[4][3];
    const int t  = threadIdx.x;
    const int n0 = blockIdx.x * 4;

    for (int i = t; i < 4 * CS; i += 256)
        s_l[i / CS][i % CS] = s[(size_t)n0 * CS + i];
    if (t < 36)            Rl[t / 9][t % 9] = rot[(size_t)n0 * 9 + t];
    else if (t < 48)       { int u = t - 36; tl[u / 3][u % 3] = trans[(size_t)n0 * 3 + u]; }
    __syncthreads();

    for (int col = t; col < 1152; col += 256) {
        const float *W, *bb_;
        int lc, nc, seg;
        if (col < 192)      { W = Wq;  bb_ = bq;  lc = col;       nc = 192; seg = 0; }
        else if (col < 384) { W = Wk;  bb_ = bk;  lc = col - 192; nc = 192; seg = 1; }
        else if (col < 576) { W = Wv;  bb_ = bv;  lc = col - 384; nc = 192; seg = 2; }
        else if (col < 720) { W = Wqp; bb_ = bqp; lc = col - 576; nc = 144; seg = 3; }
        else if (col < 864) { W = Wkp; bb_ = bkp; lc = col - 720; nc = 144; seg = 4; }
        else                { W = Wvp; bb_ = bvp; lc = col - 864; nc = 288; seg = 5; }
        float a0 = bb_[lc];
        float a1 = a0, a2 = a0, a3 = a0;
        for (int i = 0; i < CS; ++i) {
            float w = W[(size_t)i * nc + lc];
            a0 += s_l[0][i] * w;
            a1 += s_l[1][i] * w;
            a2 += s_l[2][i] * w;
            a3 += s_l[3][i] * w;
        }
        if (seg <= 2) {
            float* dst = (seg == 0 ? qs : seg == 1 ? ks : vs);
            dst[(size_t)n0 * 192 + lc] = a0;
            dst[(size_t)(n0 + 1) * 192 + lc] = a1;
            dst[(size_t)(n0 + 2) * 192 + lc] = a2;
            dst[(size_t)(n0 + 3) * 192 + lc] = a3;
        } else {
            int off = (seg == 3 ? 0 : seg == 4 ? 144 : 288);
            raw[0][off + lc] = a0; raw[1][off + lc] = a1;
            raw[2][off + lc] = a2; raw[3][off + lc] = a3;
        }
    }
    __syncthreads();

    // local -> global: out_i = sum_j R[i][j] * x_j + t_i
    for (int og = t; og < 2304; og += 256) {
        int sub = og / 576, loc5 = og % 576;
        const float* src;
        float* dst;
        int loc;
        if (loc5 < 144)      { src = &raw[sub][0];   dst = qg + (size_t)(n0 + sub) * 144; loc = loc5; }
        else if (loc5 < 288) { src = &raw[sub][144]; dst = kg + (size_t)(n0 + sub) * 144; loc = loc5 - 144; }
        else                 { src = &raw[sub][288]; dst = vg + (size_t)(n0 + sub) * 288; loc = loc5 - 288; }
        int i = loc % 3, base = loc - i;
        float v = tl[sub][i];
        for (int j = 0; j < 3; ++j) v += Rl[sub][i * 3 + j] * src[base + j];
        dst[loc] = v;
    }
}

// ---------------------------------------------------------------------------
// K2: pair bias = z @ Wb + bb, layout bias[n][h][m]
// thread per (n,m) pair
// ---------------------------------------------------------------------------
__global__ __launch_bounds__(256) void k_bias(
    const float* __restrict__ z,
    const float* __restrict__ Wb,
    const float* __restrict__ bbv,
    float* __restrict__ bias)
{
    __shared__ float4 wb4[CZ * 3];  // Wb[c][h] as float4 over h (12 = 3x float4)
    __shared__ float  bb_l[HN];
    const int t = threadIdx.x;
    for (int i = t; i < CZ * 3; i += 256)
        wb4[i] = ((const float4*)Wb)[i];
    if (t < HN) bb_l[t] = bbv[t];
    __syncthreads();

    const int nm = blockIdx.x * 256 + t;
    float acc[HN];
#pragma unroll
    for (int h = 0; h < HN; ++h) acc[h] = 0.f;

    const float4* zp = (const float4*)(z + (size_t)nm * CZ);
#pragma unroll 4
    for (int k = 0; k < 32; ++k) {
        float4 zv = zp[k];
        float zs[4] = {zv.x, zv.y, zv.z, zv.w};
#pragma unroll
        for (int d = 0; d < 4; ++d) {
            int c = k * 4 + d;
            float zc = zs[d];
#pragma unroll
            for (int q = 0; q < 3; ++q) {
                float4 w = wb4[c * 3 + q];
                acc[q * 4 + 0] += zc * w.x; acc[q * 4 + 1] += zc * w.y;
                acc[q * 4 + 2] += zc * w.z; acc[q * 4 + 3] += zc * w.w;
            }
        }
    }
    const int n = nm >> 9, m = nm & 511;
#pragma unroll
    for (int h = 0; h < HN; ++h)
        bias[((size_t)n * HN + h) * NTOK + m] = acc[h] + bb_l[h];
}

// ---------------------------------------------------------------------------
// K3: logits (scalar + point + pair bias + dist-bin + multiscale), softmax.
// block per (n,h); attn written in place over bias (block owns its row).
// ---------------------------------------------------------------------------
__global__ __launch_bounds__(256) void k_attn(
    const float* __restrict__ qs, const float* __restrict__ ks,
    const float* __restrict__ qg, const float* __restrict__ kg,
    const float* __restrict__ trans,
    const float* __restrict__ emb,
    const float* __restrict__ slog,
    const float* __restrict__ hw,
    float* __restrict__ attn)   // in: bias, out: attn
{
    const int n = blockIdx.x, h = blockIdx.y, t = threadIdx.x;
    __shared__ float ql[CH];
    __shared__ float qgl[12];
    __shared__ float tl[3];
    __shared__ float ph[3];
    __shared__ float red[8];
    if (t < CH)       ql[t] = qs[(size_t)n * 192 + h * CH + t];
    else if (t < 28)  qgl[t - 16] = qg[(size_t)n * 144 + h * 12 + (t - 16)];
    else if (t < 31)  tl[t - 28] = trans[(size_t)n * 3 + (t - 28)];
    else if (t == 31) {
        float s0 = slog[0 * HN + h], s1 = slog[1 * HN + h], s2 = slog[2 * HN + h];
        float mx = fmaxf(s0, fmaxf(s1, s2));
        float e0 = expf(s0 - mx), e1 = expf(s1 - mx), e2 = expf(s2 - mx);
        float inv = 1.f / (e0 + e1 + e2);
        ph[0] = e0 * inv; ph[1] = e1 * inv; ph[2] = e2 * inv;
    }
    __syncthreads();

    const float hwv = hw[h];
    float* arow = attn + ((size_t)n * HN + h) * NTOK;
    float lg[2];
#pragma unroll
    for (int r = 0; r < 2; ++r) {
        const int m = t + r * 256;
        // scalar logits
        const float4* kp4 = (const float4*)(ks + (size_t)m * 192 + h * CH);
        const float4* ql4 = (const float4*)ql;
        float sc = 0.f;
#pragma unroll
        for (int c = 0; c < 4; ++c) {
            float4 kv = kp4[c], qv = ql4[c];
            sc += qv.x * kv.x + qv.y * kv.y + qv.z * kv.z + qv.w * kv.w;
        }
        sc *= 0.25f;  // 1/sqrt(C_H)
        // point logits
        const float4* kg4 = (const float4*)(kg + (size_t)m * 144 + h * 12);
        const float4* qg4 = (const float4*)qgl;
        float sd = 0.f;
#pragma unroll
        for (int u = 0; u < 3; ++u) {
            float4 kv = kg4[u], qv = qg4[u];
            float d0 = qv.x - kv.x, d1 = qv.y - kv.y, d2 = qv.z - kv.z, d3 = qv.w - kv.w;
            sd += d0 * d0 + d1 * d1 + d2 * d2 + d3 * d3;
        }
        float pl = -0.5f * sd * hwv;
        // pair distance -> bin + multiscale
        float dx = tl[0] - trans[(size_t)m * 3 + 0];
        float dy = tl[1] - trans[(size_t)m * 3 + 1];
        float dz = tl[2] - trans[(size_t)m * 3 + 2];
        float dist = sqrtf(dx * dx + dy * dy + dz * dz);
        int bin = (int)ceilf(dist * 2.f) - 1;
        bin = min(63, max(0, bin));
        float db = emb[bin * HN + h];
        float ms = ph[2] + (dist <= 5.f ? ph[0] : 0.f) + ((dist > 5.f && dist <= 15.f) ? ph[1] : 0.f);
        lg[r] = sc + pl + arow[m] + db + ms;
    }

    // block softmax over 512
    float mx = fmaxf(lg[0], lg[1]);
    for (int off = 32; off; off >>= 1) mx = fmaxf(mx, __shfl_down(mx, off));
    if ((t & 63) == 0) red[t >> 6] = mx;
    __syncthreads();
    if (t == 0) red[4] = fmaxf(fmaxf(red[0], red[1]), fmaxf(red[2], red[3]));
    __syncthreads();
    mx = red[4];
    float e0 = expf(lg[0] - mx), e1 = expf(lg[1] - mx);
    float sm = e0 + e1;
    for (int off = 32; off; off >>= 1) sm += __shfl_down(sm, off);
    if ((t & 63) == 0) red[t >> 6] = sm;
    __syncthreads();
    if (t == 0) red[5] = red[0] + red[1] + red[2] + red[3];
    __syncthreads();
    const float inv = 1.f / red[5];
    arow[t] = e0 * inv;
    arow[t + 256] = e1 * inv;
}

// ---------------------------------------------------------------------------
// K4: out_scalar + out_pts_g, then global->local + norms -> feats
// block per n; attn row staged in LDS
// ---------------------------------------------------------------------------
__global__ __launch_bounds__(256) void k_out(
    const float* __restrict__ attn,
    const float* __restrict__ vs, const float* __restrict__ vg,
    const float* __restrict__ trans,
    const float* __restrict__ rot,
    float* __restrict__ feats)
{
    __shared__ float a_l[HN * NTOK];   // 24 KB
    __shared__ float sums[480];        // 12h * (16 scalar + 24 pts)
    __shared__ float Rl[9];
    __shared__ float tl[3];
    const int n = blockIdx.x, t = threadIdx.x;
    for (int i = t; i < HN * NTOK; i += 256) a_l[i] = attn[(size_t)n * HN * NTOK + i];
    if (t < 9)       Rl[t] = rot[(size_t)n * 9 + t];
    else if (t < 12) tl[t - 9] = trans[(size_t)n * 3 + (t - 9)];
    __syncthreads();

    // 480 dot products over m
    const int o0 = t;
    const int o1raw = t + 256;
    const bool act1 = o1raw < 480;
    const int o1 = act1 ? o1raw : 0;
    const int h0 = o0 / 40, j0 = o0 % 40;
    const int h1 = o1 / 40, j1 = o1 % 40;
    const float* b0; int st0;
    if (j0 < 16) { b0 = vs + h0 * 16 + j0;        st0 = 192; }
    else         { b0 = vg + h0 * 24 + (j0 - 16); st0 = 288; }
    const float* b1; int st1;
    if (j1 < 16) { b1 = vs + h1 * 16 + j1;        st1 = 192; }
    else         { b1 = vg + h1 * 24 + (j1 - 16); st1 = 288; }
    const float* a0 = a_l + h0 * NTOK;
    const float* a1 = a_l + h1 * NTOK;
    float acc0 = 0.f, acc1 = 0.f;
    for (int m = 0; m < NTOK; ++m) {
        acc0 += a0[m] * b0[(size_t)m * st0];
        acc1 += a1[m] * b1[(size_t)m * st1];
    }
    sums[o0] = acc0;
    if (act1) sums[o1raw] = acc1;
    __syncthreads();

    // epilogue: scalar copy, R^T(x - t), norms
    for (int f = t; f < 576; f += 256) {
        const int h = f / 48, j = f % 48;
        float* fp = feats + (size_t)n * FEAT_DIM + h * HSEG;
        const float* sh = sums + h * 40;
        if (j < 16) {
            fp[j] = sh[j];
        } else if (j < 40) {
            int jj = j - 16, p = jj / 3, i = jj % 3;
            float val = 0.f;
#pragma unroll
            for (int q = 0; q < 3; ++q) val += Rl[q * 3 + i] * (sh[16 + p * 3 + q] - tl[q]);
            fp[16 + jj] = val;
        } else {
            int p = j - 40;
            float s2 = 0.f;
#pragma unroll
            for (int i = 0; i < 3; ++i) {
                float val = 0.f;
#pragma unroll
                for (int q = 0; q < 3; ++q) val += Rl[q * 3 + i] * (sh[16 + p * 3 + q] - tl[q]);
                s2 += val * val;
            }
            fp[40 + p] = sqrtf(s2);
        }
    }
}

// ---------------------------------------------------------------------------
// K5: pair_feat = attn^T @ z[n]  -> feats[..., 48:176]
// block per n; thread handles 3 heads x 2 channels
// ---------------------------------------------------------------------------
__global__ __launch_bounds__(256) void k_pairfeat(
    const float* __restrict__ attn,
    const float* __restrict__ z,
    float* __restrict__ feats)
{
    __shared__ float a_l[HN * NTOK];   // 24 KB
    const int n = blockIdx.x, t = threadIdx.x;
    for (int i = t; i < HN * NTOK; i += 256) a_l[i] = attn[(size_t)n * HN * NTOK + i];
    __syncthreads();

    const int c2 = (t & 63) * 2;
    const int hb = (t >> 6) * 3;
    float acc[3][2] = {{0.f, 0.f}, {0.f, 0.f}, {0.f, 0.f}};
    const float* zp = z + (size_t)n * NTOK * CZ + c2;
    const float* ap = a_l + hb * NTOK;
    for (int m = 0; m < NTOK; ++m) {
        float2 zv = *(const float2*)(zp + (size_t)m * CZ);
#pragma unroll
        for (int u = 0; u < 3; ++u) {
            float a = ap[u * NTOK + m];
            acc[u][0] += a * zv.x;
            acc[u][1] += a * zv.y;
        }
    }
#pragma unroll
    for (int u = 0; u < 3; ++u) {
        float2 r = make_float2(acc[u][0], acc[u][1]);
        *(float2*)&feats[(size_t)n * FEAT_DIM + (hb + u) * HSEG + 48 + c2] = r;
    }
}

// ---------------------------------------------------------------------------
// K6: out = feats @ Wout + bout  (f32 output)
// block: 4 token rows x 128 output cols
// ---------------------------------------------------------------------------
__global__ __launch_bounds__(128) void k_outproj(
    const float* __restrict__ feats,
    const float* __restrict__ Wout,
    const float* __restrict__ bout,
    float* __restrict__ out)
{
    __shared__ float f_l[4 * FEAT_DIM];   // 33.8 KB
    const int t = threadIdx.x;
    const int n0 = blockIdx.x * 4;
    const int j = blockIdx.y * 128 + t;
    for (int i = t; i < 4 * FEAT_DIM; i += 128) f_l[i] = feats[(size_t)n0 * FEAT_DIM + i];
    __syncthreads();

    const float bv = bout[j];
    float acc0 = bv, acc1 = bv, acc2 = bv, acc3 = bv;
    for (int kk = 0; kk < FEAT_DIM; ++kk) {
        float w = Wout[(size_t)kk * 384 + j];
        acc0 += f_l[kk] * w;
        acc1 += f_l[FEAT_DIM + kk] * w;
        acc2 += f_l[2 * FEAT_DIM + kk] * w;
        acc3 += f_l[3 * FEAT_DIM + kk] * w;
    }
    out[(size_t)(n0 + 0) * 384 + j] = acc0;
    out[(size_t)(n0 + 1) * 384 + j] = acc1;
    out[(size_t)(n0 + 2) * 384 + j] = acc2;
    out[(size_t)(n0 + 3) * 384 + j] = acc3;
}

// ---------------------------------------------------------------------------
extern "C" void kernel_launch(void* const* d_in, const int* in_sizes, int n_in,
                              void* d_out, int out_size, void* d_ws, size_t ws_size,
                              hipStream_t stream) {
    const float* s     = (const float*)d_in[0];
    const float* z     = (const float*)d_in[1];
    const float* trans = (const float*)d_in[2];
    const float* rot   = (const float*)d_in[3];
    const float* Wq    = (const float*)d_in[4];
    const float* bq    = (const float*)d_in[5];
    const float* Wk    = (const float*)d_in[6];
    const float* bk    = (const float*)d_in[7];
    const float* Wv    = (const float*)d_in[8];
    const float* bv    = (const float*)d_in[9];
    const float* Wqp   = (const float*)d_in[10];
    const float* bqp   = (const float*)d_in[11];
    const float* Wkp   = (const float*)d_in[12];
    const float* bkp   = (const float*)d_in[13];
    const float* Wvp   = (const float*)d_in[14];
    const float* bvp   = (const float*)d_in[15];
    const float* Wb    = (const float*)d_in[16];
    const float* bb    = (const float*)d_in[17];
    const float* emb   = (const float*)d_in[18];
    const float* slog  = (const float*)d_in[19];
    const float* hw    = (const float*)d_in[20];
    const float* Wout  = (const float*)d_in[21];
    const float* bout  = (const float*)d_in[22];

    float* W = (float*)d_ws;
    float* qs    = W;                  // 512*192
    float* ks    = qs + 98304;         // 512*192
    float* vs    = ks + 98304;         // 512*192
    float* qg    = vs + 98304;         // 512*144
    float* kg    = qg + 73728;         // 512*144
    float* vg    = kg + 73728;         // 512*288
    float* bias  = vg + 147456;        // 512*12*512  (reused as attn in-place)
    float* feats = bias + 3145728;     // 512*2112
    // total: 4,816,896 floats = 19.3 MB

    k_proj<<<128, 256, 0, stream>>>(s, trans, rot, Wq, bq, Wk, bk, Wv, bv,
                                    Wqp, bqp, Wkp, bkp, Wvp, bvp,
                                    qs, ks, vs, qg, kg, vg);
    k_bias<<<1024, 256, 0, stream>>>(z, Wb, bb, bias);
    k_attn<<<dim3(512, 12), 256, 0, stream>>>(qs, ks, qg, kg, trans, emb, slog, hw, bias);
    k_out<<<512, 256, 0, stream>>>(bias, vs, vg, trans, rot, feats);
    k_pairfeat<<<512, 256, 0, stream>>>(bias, z, feats);
    k_outproj<<<dim3(128, 3), 128, 0, stream>>>(feats, Wout, bout, (float*)d_out);
}

// Round 3
// 645.966 us; speedup vs baseline: 1.1093x; 1.1093x over previous
//
#include <hip/hip_runtime.h>

#define NTOK 512
#define CS 384
#define CZ 128
#define CH 16
#define HN 12
#define PQ 4
#define PV 8
#define FEAT_DIM 2112   // HN * 176
#define HSEG 176        // 16 + 24 + 8 + 128

// ---------------------------------------------------------------------------
// K1: all projections as a tiled GEMM: [512 x 384] @ [384 x 1152(concat)]
// grid (32 token-groups of 16, 18 col-groups of 64); block 256.
// Lanes span 64 adjacent columns (coalesced W reads); the 4 waves of the
// block each own 4 tokens (wave-uniform LDS broadcast of s).
// q,k,v scalar -> qs/ks/vs; point projections -> raw_g (frame applied in K1b).
// ---------------------------------------------------------------------------
__global__ __launch_bounds__(256) void k_proj(
    const float* __restrict__ s,
    const float* __restrict__ Wq,  const float* __restrict__ bq,
    const float* __restrict__ Wk,  const float* __restrict__ bk,
    const float* __restrict__ Wv,  const float* __restrict__ bv,
    const float* __restrict__ Wqp, const float* __restrict__ bqp,
    const float* __restrict__ Wkp, const float* __restrict__ bkp,
    const float* __restrict__ Wvp, const float* __restrict__ bvp,
    float* __restrict__ qs, float* __restrict__ ks, float* __restrict__ vs,
    float* __restrict__ raw_g)
{
    __shared__ float s_l[16 * CS];   // 24 KB
    const int t  = threadIdx.x;
    const int n0 = blockIdx.x * 16;

    const float4* sg  = (const float4*)(s + (size_t)n0 * CS);
    float4*       sl4 = (float4*)s_l;
#pragma unroll
    for (int j = 0; j < 6; ++j) sl4[j * 256 + t] = sg[j * 256 + t];
    __syncthreads();

    const int col = blockIdx.y * 64 + (t & 63);
    const int tq  = t >> 6;           // wave id -> token quad (wave-uniform)

    const float *W, *bv_;
    int lc, nc;
    if (col < 192)      { W = Wq;  bv_ = bq;  lc = col;       nc = 192; }
    else if (col < 384) { W = Wk;  bv_ = bk;  lc = col - 192; nc = 192; }
    else if (col < 576) { W = Wv;  bv_ = bv;  lc = col - 384; nc = 192; }
    else if (col < 720) { W = Wqp; bv_ = bqp; lc = col - 576; nc = 144; }
    else if (col < 864) { W = Wkp; bv_ = bkp; lc = col - 720; nc = 144; }
    else                { W = Wvp; bv_ = bvp; lc = col - 864; nc = 288; }

    const float* Wp   = W + lc;
    const float* srow = s_l + tq * 4 * CS;
    float a0, a1, a2, a3;
    a0 = a1 = a2 = a3 = bv_[lc];
#pragma unroll 8
    for (int k = 0; k < CS; ++k) {
        float w = Wp[(size_t)k * nc];
        a0 += srow[k] * w;
        a1 += srow[CS + k] * w;
        a2 += srow[2 * CS + k] * w;
        a3 += srow[3 * CS + k] * w;
    }

    const int n = n0 + tq * 4;
    if (col < 576) {
        float* dst = (col < 192 ? qs : col < 384 ? ks : vs);
        dst[(size_t)(n + 0) * 192 + lc] = a0;
        dst[(size_t)(n + 1) * 192 + lc] = a1;
        dst[(size_t)(n + 2) * 192 + lc] = a2;
        dst[(size_t)(n + 3) * 192 + lc] = a3;
    } else {
        const int pc = col - 576;   // qp[0:144) kp[144:288) vp[288:576)
        raw_g[(size_t)(n + 0) * 576 + pc] = a0;
        raw_g[(size_t)(n + 1) * 576 + pc] = a1;
        raw_g[(size_t)(n + 2) * 576 + pc] = a2;
        raw_g[(size_t)(n + 3) * 576 + pc] = a3;
    }
}

// ---------------------------------------------------------------------------
// K1b: apply frame (local -> global): out_i = sum_j R[i][j] x_j + t_i
// one thread per output element of raw_g [512][576]
// ---------------------------------------------------------------------------
__global__ __launch_bounds__(256) void k_frame(
    const float* __restrict__ raw_g,
    const float* __restrict__ trans,
    const float* __restrict__ rot,
    float* __restrict__ qg, float* __restrict__ kg, float* __restrict__ vg)
{
    const int e = blockIdx.x * 256 + threadIdx.x;   // < 512*576
    const int n = e / 576, loc = e % 576;
    const int i = loc % 3, base = loc - i;
    const float* rp = raw_g + (size_t)n * 576 + base;
    float x0 = rp[0], x1 = rp[1], x2 = rp[2];
    const float* R = rot + (size_t)n * 9 + i * 3;
    float v = trans[(size_t)n * 3 + i] + R[0] * x0 + R[1] * x1 + R[2] * x2;
    if (loc < 144)      qg[(size_t)n * 144 + loc] = v;
    else if (loc < 288) kg[(size_t)n * 144 + loc - 144] = v;
    else                vg[(size_t)n * 288 + loc - 288] = v;
}

// ---------------------------------------------------------------------------
// K2: pair bias = z @ Wb + bb, layout bias[n][h][m]
// block = 64 contiguous (n,m) rows: the 64x128 f32 tile is contiguous 32 KB
// in global -> fully coalesced float4 staging; compute reads LDS rows
// (pad 132 floats), Wb is wave-uniform broadcast.
// ---------------------------------------------------------------------------
__global__ __launch_bounds__(256) void k_bias(
    const float* __restrict__ z,
    const float* __restrict__ Wb,
    const float* __restrict__ bbv,
    float* __restrict__ bias)
{
    __shared__ float a_l[64 * 132];     // 33.8 KB, padded rows
    __shared__ float wb_l[CZ * HN];     // 6 KB, [k][h]
    __shared__ float bb_l[HN];
    const int t = threadIdx.x;
    for (int i = t; i < CZ * HN; i += 256) wb_l[i] = Wb[i];
    if (t < HN) bb_l[t] = bbv[t];

    const float4* zg = (const float4*)(z + (size_t)blockIdx.x * 64 * CZ);
#pragma unroll
    for (int j = 0; j < 8; ++j) {
        const int f4i = j * 256 + t;            // 0..2047
        const int row = f4i >> 5, c4 = f4i & 31;
        *(float4*)&a_l[row * 132 + c4 * 4] = zg[f4i];
    }
    __syncthreads();

    const int row = t & 63;
    const int hg  = t >> 6;          // wave-uniform head triple
    float acc0 = 0.f, acc1 = 0.f, acc2 = 0.f;
    const float4* ar = (const float4*)&a_l[row * 132];
    const float*  wr = wb_l + hg * 3;
#pragma unroll 8
    for (int k4 = 0; k4 < 32; ++k4) {
        float4 zv = ar[k4];
        float zs[4] = {zv.x, zv.y, zv.z, zv.w};
#pragma unroll
        for (int e = 0; e < 4; ++e) {
            const float* w = wr + (k4 * 4 + e) * HN;
            acc0 += zs[e] * w[0];
            acc1 += zs[e] * w[1];
            acc2 += zs[e] * w[2];
        }
    }
    const int grow = blockIdx.x * 64 + row;     // n*512 + m
    const int n = grow >> 9, m = grow & 511;
    const int h = hg * 3;
    bias[((size_t)n * HN + h + 0) * NTOK + m] = acc0 + bb_l[h + 0];
    bias[((size_t)n * HN + h + 1) * NTOK + m] = acc1 + bb_l[h + 1];
    bias[((size_t)n * HN + h + 2) * NTOK + m] = acc2 + bb_l[h + 2];
}

// ---------------------------------------------------------------------------
// K3: logits (scalar + point + pair bias + dist-bin + multiscale), softmax.
// block per (n,h); attn written in place over bias (block owns its row).
// ---------------------------------------------------------------------------
__global__ __launch_bounds__(256) void k_attn(
    const float* __restrict__ qs, const float* __restrict__ ks,
    const float* __restrict__ qg, const float* __restrict__ kg,
    const float* __restrict__ trans,
    const float* __restrict__ emb,
    const float* __restrict__ slog,
    const float* __restrict__ hw,
    float* __restrict__ attn)   // in: bias, out: attn
{
    const int n = blockIdx.x, h = blockIdx.y, t = threadIdx.x;
    __shared__ float ql[CH];
    __shared__ float qgl[12];
    __shared__ float tl[3];
    __shared__ float ph[3];
    __shared__ float red[8];
    if (t < CH)       ql[t] = qs[(size_t)n * 192 + h * CH + t];
    else if (t < 28)  qgl[t - 16] = qg[(size_t)n * 144 + h * 12 + (t - 16)];
    else if (t < 31)  tl[t - 28] = trans[(size_t)n * 3 + (t - 28)];
    else if (t == 31) {
        float s0 = slog[0 * HN + h], s1 = slog[1 * HN + h], s2 = slog[2 * HN + h];
        float mx = fmaxf(s0, fmaxf(s1, s2));
        float e0 = expf(s0 - mx), e1 = expf(s1 - mx), e2 = expf(s2 - mx);
        float inv = 1.f / (e0 + e1 + e2);
        ph[0] = e0 * inv; ph[1] = e1 * inv; ph[2] = e2 * inv;
    }
    __syncthreads();

    const float hwv = hw[h];
    float* arow = attn + ((size_t)n * HN + h) * NTOK;
    float lg[2];
#pragma unroll
    for (int r = 0; r < 2; ++r) {
        const int m = t + r * 256;
        // scalar logits
        const float4* kp4 = (const float4*)(ks + (size_t)m * 192 + h * CH);
        const float4* ql4 = (const float4*)ql;
        float sc = 0.f;
#pragma unroll
        for (int c = 0; c < 4; ++c) {
            float4 kv = kp4[c], qv = ql4[c];
            sc += qv.x * kv.x + qv.y * kv.y + qv.z * kv.z + qv.w * kv.w;
        }
        sc *= 0.25f;  // 1/sqrt(C_H)
        // point logits
        const float4* kg4 = (const float4*)(kg + (size_t)m * 144 + h * 12);
        const float4* qg4 = (const float4*)qgl;
        float sd = 0.f;
#pragma unroll
        for (int u = 0; u < 3; ++u) {
            float4 kv = kg4[u], qv = qg4[u];
            float d0 = qv.x - kv.x, d1 = qv.y - kv.y, d2 = qv.z - kv.z, d3 = qv.w - kv.w;
            sd += d0 * d0 + d1 * d1 + d2 * d2 + d3 * d3;
        }
        float pl = -0.5f * sd * hwv;
        // pair distance -> bin + multiscale
        float dx = tl[0] - trans[(size_t)m * 3 + 0];
        float dy = tl[1] - trans[(size_t)m * 3 + 1];
        float dz = tl[2] - trans[(size_t)m * 3 + 2];
        float dist = sqrtf(dx * dx + dy * dy + dz * dz);
        int bin = (int)ceilf(dist * 2.f) - 1;
        bin = min(63, max(0, bin));
        float db = emb[bin * HN + h];
        float ms = ph[2] + (dist <= 5.f ? ph[0] : 0.f) + ((dist > 5.f && dist <= 15.f) ? ph[1] : 0.f);
        lg[r] = sc + pl + arow[m] + db + ms;
    }

    // block softmax over 512
    float mx = fmaxf(lg[0], lg[1]);
    for (int off = 32; off; off >>= 1) mx = fmaxf(mx, __shfl_down(mx, off));
    if ((t & 63) == 0) red[t >> 6] = mx;
    __syncthreads();
    if (t == 0) red[4] = fmaxf(fmaxf(red[0], red[1]), fmaxf(red[2], red[3]));
    __syncthreads();
    mx = red[4];
    float e0 = expf(lg[0] - mx), e1 = expf(lg[1] - mx);
    float sm = e0 + e1;
    for (int off = 32; off; off >>= 1) sm += __shfl_down(sm, off);
    if ((t & 63) == 0) red[t >> 6] = sm;
    __syncthreads();
    if (t == 0) red[5] = red[0] + red[1] + red[2] + red[3];
    __syncthreads();
    const float inv = 1.f / red[5];
    arow[t] = e0 * inv;
    arow[t + 256] = e1 * inv;
}

// ---------------------------------------------------------------------------
// K4: out_scalar + out_pts_g, then global->local + norms -> feats
// block per n; attn row staged in LDS
// ---------------------------------------------------------------------------
__global__ __launch_bounds__(256) void k_out(
    const float* __restrict__ attn,
    const float* __restrict__ vs, const float* __restrict__ vg,
    const float* __restrict__ trans,
    const float* __restrict__ rot,
    float* __restrict__ feats)
{
    __shared__ float a_l[HN * NTOK];   // 24 KB
    __shared__ float sums[480];        // 12h * (16 scalar + 24 pts)
    __shared__ float Rl[9];
    __shared__ float tl[3];
    const int n = blockIdx.x, t = threadIdx.x;
    for (int i = t; i < HN * NTOK; i += 256) a_l[i] = attn[(size_t)n * HN * NTOK + i];
    if (t < 9)       Rl[t] = rot[(size_t)n * 9 + t];
    else if (t < 12) tl[t - 9] = trans[(size_t)n * 3 + (t - 9)];
    __syncthreads();

    // 480 dot products over m
    const int o0 = t;
    const int o1raw = t + 256;
    const bool act1 = o1raw < 480;
    const int o1 = act1 ? o1raw : 0;
    const int h0 = o0 / 40, j0 = o0 % 40;
    const int h1 = o1 / 40, j1 = o1 % 40;
    const float* b0; int st0;
    if (j0 < 16) { b0 = vs + h0 * 16 + j0;        st0 = 192; }
    else         { b0 = vg + h0 * 24 + (j0 - 16); st0 = 288; }
    const float* b1; int st1;
    if (j1 < 16) { b1 = vs + h1 * 16 + j1;        st1 = 192; }
    else         { b1 = vg + h1 * 24 + (j1 - 16); st1 = 288; }
    const float* a0 = a_l + h0 * NTOK;
    const float* a1 = a_l + h1 * NTOK;
    float acc0 = 0.f, acc1 = 0.f;
#pragma unroll 8
    for (int m = 0; m < NTOK; ++m) {
        acc0 += a0[m] * b0[(size_t)m * st0];
        acc1 += a1[m] * b1[(size_t)m * st1];
    }
    sums[o0] = acc0;
    if (act1) sums[o1raw] = acc1;
    __syncthreads();

    // epilogue: scalar copy, R^T(x - t), norms
    for (int f = t; f < 576; f += 256) {
        const int h = f / 48, j = f % 48;
        float* fp = feats + (size_t)n * FEAT_DIM + h * HSEG;
        const float* sh = sums + h * 40;
        if (j < 16) {
            fp[j] = sh[j];
        } else if (j < 40) {
            int jj = j - 16, p = jj / 3, i = jj % 3;
            float val = 0.f;
#pragma unroll
            for (int q = 0; q < 3; ++q) val += Rl[q * 3 + i] * (sh[16 + p * 3 + q] - tl[q]);
            fp[16 + jj] = val;
        } else {
            int p = j - 40;
            float s2 = 0.f;
#pragma unroll
            for (int i = 0; i < 3; ++i) {
                float val = 0.f;
#pragma unroll
                for (int q = 0; q < 3; ++q) val += Rl[q * 3 + i] * (sh[16 + p * 3 + q] - tl[q]);
                s2 += val * val;
            }
            fp[40 + p] = sqrtf(s2);
        }
    }
}

// ---------------------------------------------------------------------------
// K5: pair_feat = attn^T @ z[n]  -> feats[..., 48:176]
// block per n; thread handles 3 heads x 2 channels
// ---------------------------------------------------------------------------
__global__ __launch_bounds__(256) void k_pairfeat(
    const float* __restrict__ attn,
    const float* __restrict__ z,
    float* __restrict__ feats)
{
    __shared__ float a_l[HN * NTOK];   // 24 KB
    const int n = blockIdx.x, t = threadIdx.x;
    for (int i = t; i < HN * NTOK; i += 256) a_l[i] = attn[(size_t)n * HN * NTOK + i];
    __syncthreads();

    const int c2 = (t & 63) * 2;
    const int hb = (t >> 6) * 3;
    float acc[3][2] = {{0.f, 0.f}, {0.f, 0.f}, {0.f, 0.f}};
    const float* zp = z + (size_t)n * NTOK * CZ + c2;
    const float* ap = a_l + hb * NTOK;
#pragma unroll 4
    for (int m = 0; m < NTOK; ++m) {
        float2 zv = *(const float2*)(zp + (size_t)m * CZ);
#pragma unroll
        for (int u = 0; u < 3; ++u) {
            float a = ap[u * NTOK + m];
            acc[u][0] += a * zv.x;
            acc[u][1] += a * zv.y;
        }
    }
#pragma unroll
    for (int u = 0; u < 3; ++u) {
        float2 r = make_float2(acc[u][0], acc[u][1]);
        *(float2*)&feats[(size_t)n * FEAT_DIM + (hb + u) * HSEG + 48 + c2] = r;
    }
}

// ---------------------------------------------------------------------------
// K6: out = feats @ Wout + bout  (f32 output)
// block: 4 token rows x 128 output cols
// ---------------------------------------------------------------------------
__global__ __launch_bounds__(128) void k_outproj(
    const float* __restrict__ feats,
    const float* __restrict__ Wout,
    const float* __restrict__ bout,
    float* __restrict__ out)
{
    __shared__ float f_l[4 * FEAT_DIM];   // 33.8 KB
    const int t = threadIdx.x;
    const int n0 = blockIdx.x * 4;
    const int j = blockIdx.y * 128 + t;
    for (int i = t; i < 4 * FEAT_DIM; i += 128) f_l[i] = feats[(size_t)n0 * FEAT_DIM + i];
    __syncthreads();

    const float bv = bout[j];
    float acc0 = bv, acc1 = bv, acc2 = bv, acc3 = bv;
#pragma unroll 4
    for (int kk = 0; kk < FEAT_DIM; ++kk) {
        float w = Wout[(size_t)kk * 384 + j];
        acc0 += f_l[kk] * w;
        acc1 += f_l[FEAT_DIM + kk] * w;
        acc2 += f_l[2 * FEAT_DIM + kk] * w;
        acc3 += f_l[3 * FEAT_DIM + kk] * w;
    }
    out[(size_t)(n0 + 0) * 384 + j] = acc0;
    out[(size_t)(n0 + 1) * 384 + j] = acc1;
    out[(size_t)(n0 + 2) * 384 + j] = acc2;
    out[(size_t)(n0 + 3) * 384 + j] = acc3;
}

// ---------------------------------------------------------------------------
extern "C" void kernel_launch(void* const* d_in, const int* in_sizes, int n_in,
                              void* d_out, int out_size, void* d_ws, size_t ws_size,
                              hipStream_t stream) {
    const float* s     = (const float*)d_in[0];
    const float* z     = (const float*)d_in[1];
    const float* trans = (const float*)d_in[2];
    const float* rot   = (const float*)d_in[3];
    const float* Wq    = (const float*)d_in[4];
    const float* bq    = (const float*)d_in[5];
    const float* Wk    = (const float*)d_in[6];
    const float* bk    = (const float*)d_in[7];
    const float* Wv    = (const float*)d_in[8];
    const float* bv    = (const float*)d_in[9];
    const float* Wqp   = (const float*)d_in[10];
    const float* bqp   = (const float*)d_in[11];
    const float* Wkp   = (const float*)d_in[12];
    const float* bkp   = (const float*)d_in[13];
    const float* Wvp   = (const float*)d_in[14];
    const float* bvp   = (const float*)d_in[15];
    const float* Wb    = (const float*)d_in[16];
    const float* bb    = (const float*)d_in[17];
    const float* emb   = (const float*)d_in[18];
    const float* slog  = (const float*)d_in[19];
    const float* hw    = (const float*)d_in[20];
    const float* Wout  = (const float*)d_in[21];
    const float* bout  = (const float*)d_in[22];

    float* W = (float*)d_ws;
    float* qs    = W;                  // 512*192
    float* ks    = qs + 98304;         // 512*192
    float* vs    = ks + 98304;         // 512*192
    float* qg    = vs + 98304;         // 512*144
    float* kg    = qg + 73728;         // 512*144
    float* vg    = kg + 73728;         // 512*288
    float* bias  = vg + 147456;        // 512*12*512  (reused as attn in-place)
    float* feats = bias + 3145728;     // 512*2112
    float* raw_g = feats + 1081344;    // 512*576
    // total: ~5.1M floats = 20.5 MB

    k_proj<<<dim3(32, 18), 256, 0, stream>>>(s, Wq, bq, Wk, bk, Wv, bv,
                                             Wqp, bqp, Wkp, bkp, Wvp, bvp,
                                             qs, ks, vs, raw_g);
    k_frame<<<1152, 256, 0, stream>>>(raw_g, trans, rot, qg, kg, vg);
    k_bias<<<4096, 256, 0, stream>>>(z, Wb, bb, bias);
    k_attn<<<dim3(512, 12), 256, 0, stream>>>(qs, ks, qg, kg, trans, emb, slog, hw, bias);
    k_out<<<512, 256, 0, stream>>>(bias, vs, vg, trans, rot, feats);
    k_pairfeat<<<512, 256, 0, stream>>>(bias, z, feats);
    k_outproj<<<dim3(128, 3), 128, 0, stream>>>(feats, Wout, bout, (float*)d_out);
}

// Round 4
// 545.559 us; speedup vs baseline: 1.3134x; 1.1840x over previous
//
#include <hip/hip_runtime.h>

#define NTOK 512
#define CS 384
#define CZ 128
#define CH 16
#define HN 12
#define PQ 4
#define PV 8
#define FEAT_DIM 2112   // HN * 176
#define HSEG 176        // 16 + 24 + 8 + 128

// ---------------------------------------------------------------------------
// K1: all projections as a tiled GEMM: [512 x 384] @ [384 x 1152(concat)]
// grid (32 token-groups of 16, 18 col-groups of 64); block 256.
// ---------------------------------------------------------------------------
__global__ __launch_bounds__(256) void k_proj(
    const float* __restrict__ s,
    const float* __restrict__ Wq,  const float* __restrict__ bq,
    const float* __restrict__ Wk,  const float* __restrict__ bk,
    const float* __restrict__ Wv,  const float* __restrict__ bv,
    const float* __restrict__ Wqp, const float* __restrict__ bqp,
    const float* __restrict__ Wkp, const float* __restrict__ bkp,
    const float* __restrict__ Wvp, const float* __restrict__ bvp,
    float* __restrict__ qs, float* __restrict__ ks, float* __restrict__ vs,
    float* __restrict__ raw_g)
{
    __shared__ float s_l[16 * CS];   // 24 KB
    const int t  = threadIdx.x;
    const int n0 = blockIdx.x * 16;

    const float4* sg  = (const float4*)(s + (size_t)n0 * CS);
    float4*       sl4 = (float4*)s_l;
#pragma unroll
    for (int j = 0; j < 6; ++j) sl4[j * 256 + t] = sg[j * 256 + t];
    __syncthreads();

    const int col = blockIdx.y * 64 + (t & 63);
    const int tq  = t >> 6;           // wave id -> token quad (wave-uniform)

    const float *W, *bv_;
    int lc, nc;
    if (col < 192)      { W = Wq;  bv_ = bq;  lc = col;       nc = 192; }
    else if (col < 384) { W = Wk;  bv_ = bk;  lc = col - 192; nc = 192; }
    else if (col < 576) { W = Wv;  bv_ = bv;  lc = col - 384; nc = 192; }
    else if (col < 720) { W = Wqp; bv_ = bqp; lc = col - 576; nc = 144; }
    else if (col < 864) { W = Wkp; bv_ = bkp; lc = col - 720; nc = 144; }
    else                { W = Wvp; bv_ = bvp; lc = col - 864; nc = 288; }

    const float* Wp   = W + lc;
    const float* srow = s_l + tq * 4 * CS;
    float a0, a1, a2, a3;
    a0 = a1 = a2 = a3 = bv_[lc];
#pragma unroll 8
    for (int k = 0; k < CS; ++k) {
        float w = Wp[(size_t)k * nc];
        a0 += srow[k] * w;
        a1 += srow[CS + k] * w;
        a2 += srow[2 * CS + k] * w;
        a3 += srow[3 * CS + k] * w;
    }

    const int n = n0 + tq * 4;
    if (col < 576) {
        float* dst = (col < 192 ? qs : col < 384 ? ks : vs);
        dst[(size_t)(n + 0) * 192 + lc] = a0;
        dst[(size_t)(n + 1) * 192 + lc] = a1;
        dst[(size_t)(n + 2) * 192 + lc] = a2;
        dst[(size_t)(n + 3) * 192 + lc] = a3;
    } else {
        const int pc = col - 576;   // qp[0:144) kp[144:288) vp[288:576)
        raw_g[(size_t)(n + 0) * 576 + pc] = a0;
        raw_g[(size_t)(n + 1) * 576 + pc] = a1;
        raw_g[(size_t)(n + 2) * 576 + pc] = a2;
        raw_g[(size_t)(n + 3) * 576 + pc] = a3;
    }
}

// ---------------------------------------------------------------------------
// K1b: apply frame (local -> global): out_i = sum_j R[i][j] x_j + t_i
// ---------------------------------------------------------------------------
__global__ __launch_bounds__(256) void k_frame(
    const float* __restrict__ raw_g,
    const float* __restrict__ trans,
    const float* __restrict__ rot,
    float* __restrict__ qg, float* __restrict__ kg, float* __restrict__ vg)
{
    const int e = blockIdx.x * 256 + threadIdx.x;   // < 512*576
    const int n = e / 576, loc = e % 576;
    const int i = loc % 3, base = loc - i;
    const float* rp = raw_g + (size_t)n * 576 + base;
    float x0 = rp[0], x1 = rp[1], x2 = rp[2];
    const float* R = rot + (size_t)n * 9 + i * 3;
    float v = trans[(size_t)n * 3 + i] + R[0] * x0 + R[1] * x1 + R[2] * x2;
    if (loc < 144)      qg[(size_t)n * 144 + loc] = v;
    else if (loc < 288) kg[(size_t)n * 144 + loc - 144] = v;
    else                vg[(size_t)n * 288 + loc - 288] = v;
}

// ---------------------------------------------------------------------------
// K2: pair bias = z @ Wb + bb, layout bias[n][h][m]
// ---------------------------------------------------------------------------
__global__ __launch_bounds__(256) void k_bias(
    const float* __restrict__ z,
    const float* __restrict__ Wb,
    const float* __restrict__ bbv,
    float* __restrict__ bias)
{
    __shared__ float a_l[64 * 132];     // 33.8 KB, padded rows
    __shared__ float wb_l[CZ * HN];     // 6 KB, [k][h]
    __shared__ float bb_l[HN];
    const int t = threadIdx.x;
    for (int i = t; i < CZ * HN; i += 256) wb_l[i] = Wb[i];
    if (t < HN) bb_l[t] = bbv[t];

    const float4* zg = (const float4*)(z + (size_t)blockIdx.x * 64 * CZ);
#pragma unroll
    for (int j = 0; j < 8; ++j) {
        const int f4i = j * 256 + t;            // 0..2047
        const int row = f4i >> 5, c4 = f4i & 31;
        *(float4*)&a_l[row * 132 + c4 * 4] = zg[f4i];
    }
    __syncthreads();

    const int row = t & 63;
    const int hg  = t >> 6;          // wave-uniform head triple
    float acc0 = 0.f, acc1 = 0.f, acc2 = 0.f;
    const float4* ar = (const float4*)&a_l[row * 132];
    const float*  wr = wb_l + hg * 3;
#pragma unroll 8
    for (int k4 = 0; k4 < 32; ++k4) {
        float4 zv = ar[k4];
        float zs[4] = {zv.x, zv.y, zv.z, zv.w};
#pragma unroll
        for (int e = 0; e < 4; ++e) {
            const float* w = wr + (k4 * 4 + e) * HN;
            acc0 += zs[e] * w[0];
            acc1 += zs[e] * w[1];
            acc2 += zs[e] * w[2];
        }
    }
    const int grow = blockIdx.x * 64 + row;     // n*512 + m
    const int n = grow >> 9, m = grow & 511;
    const int h = hg * 3;
    bias[((size_t)n * HN + h + 0) * NTOK + m] = acc0 + bb_l[h + 0];
    bias[((size_t)n * HN + h + 1) * NTOK + m] = acc1 + bb_l[h + 1];
    bias[((size_t)n * HN + h + 2) * NTOK + m] = acc2 + bb_l[h + 2];
}

// ---------------------------------------------------------------------------
// K3: logits (scalar + point + pair bias + dist-bin + multiscale), softmax.
// ---------------------------------------------------------------------------
__global__ __launch_bounds__(256) void k_attn(
    const float* __restrict__ qs, const float* __restrict__ ks,
    const float* __restrict__ qg, const float* __restrict__ kg,
    const float* __restrict__ trans,
    const float* __restrict__ emb,
    const float* __restrict__ slog,
    const float* __restrict__ hw,
    float* __restrict__ attn)   // in: bias, out: attn
{
    const int n = blockIdx.x, h = blockIdx.y, t = threadIdx.x;
    __shared__ float ql[CH];
    __shared__ float qgl[12];
    __shared__ float tl[3];
    __shared__ float ph[3];
    __shared__ float red[8];
    if (t < CH)       ql[t] = qs[(size_t)n * 192 + h * CH + t];
    else if (t < 28)  qgl[t - 16] = qg[(size_t)n * 144 + h * 12 + (t - 16)];
    else if (t < 31)  tl[t - 28] = trans[(size_t)n * 3 + (t - 28)];
    else if (t == 31) {
        float s0 = slog[0 * HN + h], s1 = slog[1 * HN + h], s2 = slog[2 * HN + h];
        float mx = fmaxf(s0, fmaxf(s1, s2));
        float e0 = expf(s0 - mx), e1 = expf(s1 - mx), e2 = expf(s2 - mx);
        float inv = 1.f / (e0 + e1 + e2);
        ph[0] = e0 * inv; ph[1] = e1 * inv; ph[2] = e2 * inv;
    }
    __syncthreads();

    const float hwv = hw[h];
    float* arow = attn + ((size_t)n * HN + h) * NTOK;
    float lg[2];
#pragma unroll
    for (int r = 0; r < 2; ++r) {
        const int m = t + r * 256;
        // scalar logits
        const float4* kp4 = (const float4*)(ks + (size_t)m * 192 + h * CH);
        const float4* ql4 = (const float4*)ql;
        float sc = 0.f;
#pragma unroll
        for (int c = 0; c < 4; ++c) {
            float4 kv = kp4[c], qv = ql4[c];
            sc += qv.x * kv.x + qv.y * kv.y + qv.z * kv.z + qv.w * kv.w;
        }
        sc *= 0.25f;  // 1/sqrt(C_H)
        // point logits
        const float4* kg4 = (const float4*)(kg + (size_t)m * 144 + h * 12);
        const float4* qg4 = (const float4*)qgl;
        float sd = 0.f;
#pragma unroll
        for (int u = 0; u < 3; ++u) {
            float4 kv = kg4[u], qv = qg4[u];
            float d0 = qv.x - kv.x, d1 = qv.y - kv.y, d2 = qv.z - kv.z, d3 = qv.w - kv.w;
            sd += d0 * d0 + d1 * d1 + d2 * d2 + d3 * d3;
        }
        float pl = -0.5f * sd * hwv;
        // pair distance -> bin + multiscale
        float dx = tl[0] - trans[(size_t)m * 3 + 0];
        float dy = tl[1] - trans[(size_t)m * 3 + 1];
        float dz = tl[2] - trans[(size_t)m * 3 + 2];
        float dist = sqrtf(dx * dx + dy * dy + dz * dz);
        int bin = (int)ceilf(dist * 2.f) - 1;
        bin = min(63, max(0, bin));
        float db = emb[bin * HN + h];
        float ms = ph[2] + (dist <= 5.f ? ph[0] : 0.f) + ((dist > 5.f && dist <= 15.f) ? ph[1] : 0.f);
        lg[r] = sc + pl + arow[m] + db + ms;
    }

    // block softmax over 512
    float mx = fmaxf(lg[0], lg[1]);
    for (int off = 32; off; off >>= 1) mx = fmaxf(mx, __shfl_down(mx, off));
    if ((t & 63) == 0) red[t >> 6] = mx;
    __syncthreads();
    if (t == 0) red[4] = fmaxf(fmaxf(red[0], red[1]), fmaxf(red[2], red[3]));
    __syncthreads();
    mx = red[4];
    float e0 = expf(lg[0] - mx), e1 = expf(lg[1] - mx);
    float sm = e0 + e1;
    for (int off = 32; off; off >>= 1) sm += __shfl_down(sm, off);
    if ((t & 63) == 0) red[t >> 6] = sm;
    __syncthreads();
    if (t == 0) red[5] = red[0] + red[1] + red[2] + red[3];
    __syncthreads();
    const float inv = 1.f / red[5];
    arow[t] = e0 * inv;
    arow[t + 256] = e1 * inv;
}

// ---------------------------------------------------------------------------
// K4: out_scalar + out_pts_g, then global->local + norms -> feats
// ---------------------------------------------------------------------------
__global__ __launch_bounds__(256) void k_out(
    const float* __restrict__ attn,
    const float* __restrict__ vs, const float* __restrict__ vg,
    const float* __restrict__ trans,
    const float* __restrict__ rot,
    float* __restrict__ feats)
{
    __shared__ float a_l[HN * NTOK];   // 24 KB
    __shared__ float sums[480];        // 12h * (16 scalar + 24 pts)
    __shared__ float Rl[9];
    __shared__ float tl[3];
    const int n = blockIdx.x, t = threadIdx.x;
    for (int i = t; i < HN * NTOK; i += 256) a_l[i] = attn[(size_t)n * HN * NTOK + i];
    if (t < 9)       Rl[t] = rot[(size_t)n * 9 + t];
    else if (t < 12) tl[t - 9] = trans[(size_t)n * 3 + (t - 9)];
    __syncthreads();

    // 480 dot products over m
    const int o0 = t;
    const int o1raw = t + 256;
    const bool act1 = o1raw < 480;
    const int o1 = act1 ? o1raw : 0;
    const int h0 = o0 / 40, j0 = o0 % 40;
    const int h1 = o1 / 40, j1 = o1 % 40;
    const float* b0; int st0;
    if (j0 < 16) { b0 = vs + h0 * 16 + j0;        st0 = 192; }
    else         { b0 = vg + h0 * 24 + (j0 - 16); st0 = 288; }
    const float* b1; int st1;
    if (j1 < 16) { b1 = vs + h1 * 16 + j1;        st1 = 192; }
    else         { b1 = vg + h1 * 24 + (j1 - 16); st1 = 288; }
    const float* a0 = a_l + h0 * NTOK;
    const float* a1 = a_l + h1 * NTOK;
    float acc0 = 0.f, acc1 = 0.f;
#pragma unroll 8
    for (int m = 0; m < NTOK; ++m) {
        acc0 += a0[m] * b0[(size_t)m * st0];
        acc1 += a1[m] * b1[(size_t)m * st1];
    }
    sums[o0] = acc0;
    if (act1) sums[o1raw] = acc1;
    __syncthreads();

    // epilogue: scalar copy, R^T(x - t), norms
    for (int f = t; f < 576; f += 256) {
        const int h = f / 48, j = f % 48;
        float* fp = feats + (size_t)n * FEAT_DIM + h * HSEG;
        const float* sh = sums + h * 40;
        if (j < 16) {
            fp[j] = sh[j];
        } else if (j < 40) {
            int jj = j - 16, p = jj / 3, i = jj % 3;
            float val = 0.f;
#pragma unroll
            for (int q = 0; q < 3; ++q) val += Rl[q * 3 + i] * (sh[16 + p * 3 + q] - tl[q]);
            fp[16 + jj] = val;
        } else {
            int p = j - 40;
            float s2 = 0.f;
#pragma unroll
            for (int i = 0; i < 3; ++i) {
                float val = 0.f;
#pragma unroll
                for (int q = 0; q < 3; ++q) val += Rl[q * 3 + i] * (sh[16 + p * 3 + q] - tl[q]);
                s2 += val * val;
            }
            fp[40 + p] = sqrtf(s2);
        }
    }
}

// ---------------------------------------------------------------------------
// K5: pair_feat = attn^T @ z[n]  -> feats[..., 48:176]
// ---------------------------------------------------------------------------
__global__ __launch_bounds__(256) void k_pairfeat(
    const float* __restrict__ attn,
    const float* __restrict__ z,
    float* __restrict__ feats)
{
    __shared__ float a_l[HN * NTOK];   // 24 KB
    const int n = blockIdx.x, t = threadIdx.x;
    for (int i = t; i < HN * NTOK; i += 256) a_l[i] = attn[(size_t)n * HN * NTOK + i];
    __syncthreads();

    const int c2 = (t & 63) * 2;
    const int hb = (t >> 6) * 3;
    float acc[3][2] = {{0.f, 0.f}, {0.f, 0.f}, {0.f, 0.f}};
    const float* zp = z + (size_t)n * NTOK * CZ + c2;
    const float* ap = a_l + hb * NTOK;
#pragma unroll 4
    for (int m = 0; m < NTOK; ++m) {
        float2 zv = *(const float2*)(zp + (size_t)m * CZ);
#pragma unroll
        for (int u = 0; u < 3; ++u) {
            float a = ap[u * NTOK + m];
            acc[u][0] += a * zv.x;
            acc[u][1] += a * zv.y;
        }
    }
#pragma unroll
    for (int u = 0; u < 3; ++u) {
        float2 r = make_float2(acc[u][0], acc[u][1]);
        *(float2*)&feats[(size_t)n * FEAT_DIM + (hb + u) * HSEG + 48 + c2] = r;
    }
}

// ---------------------------------------------------------------------------
// K6: out = feats @ Wout + bout  (f32 output)
// grid (128 token-quads, 6 col-groups of 64) = 768 blocks; block = 4 waves.
// Wave w owns token n0+w; lanes own 64 adjacent cols -> coalesced W loads;
// feats tile staged in LDS, read as wave-uniform broadcast. unroll 8 for MLP.
// ---------------------------------------------------------------------------
__global__ __launch_bounds__(256) void k_outproj(
    const float* __restrict__ feats,
    const float* __restrict__ Wout,
    const float* __restrict__ bout,
    float* __restrict__ out)
{
    __shared__ float f_l[4 * FEAT_DIM];   // 33.8 KB
    const int t  = threadIdx.x;
    const int n0 = blockIdx.x * 4;
    const int wv = t >> 6;                        // wave -> token (uniform)
    const int j  = blockIdx.y * 64 + (t & 63);    // output column

    const float4* fg  = (const float4*)(feats + (size_t)n0 * FEAT_DIM);
    float4*       fl4 = (float4*)f_l;
    for (int i = t; i < FEAT_DIM; i += 256) fl4[i] = fg[i];   // 2112 float4s
    __syncthreads();

    const float* fr = f_l + wv * FEAT_DIM;
    const float* Wp = Wout + j;
    float acc = bout[j];
#pragma unroll 8
    for (int k = 0; k < FEAT_DIM; ++k)
        acc += fr[k] * Wp[(size_t)k * 384];
    out[(size_t)(n0 + wv) * 384 + j] = acc;
}

// ---------------------------------------------------------------------------
extern "C" void kernel_launch(void* const* d_in, const int* in_sizes, int n_in,
                              void* d_out, int out_size, void* d_ws, size_t ws_size,
                              hipStream_t stream) {
    const float* s     = (const float*)d_in[0];
    const float* z     = (const float*)d_in[1];
    const float* trans = (const float*)d_in[2];
    const float* rot   = (const float*)d_in[3];
    const float* Wq    = (const float*)d_in[4];
    const float* bq    = (const float*)d_in[5];
    const float* Wk    = (const float*)d_in[6];
    const float* bk    = (const float*)d_in[7];
    const float* Wv    = (const float*)d_in[8];
    const float* bv    = (const float*)d_in[9];
    const float* Wqp   = (const float*)d_in[10];
    const float* bqp   = (const float*)d_in[11];
    const float* Wkp   = (const float*)d_in[12];
    const float* bkp   = (const float*)d_in[13];
    const float* Wvp   = (const float*)d_in[14];
    const float* bvp   = (const float*)d_in[15];
    const float* Wb    = (const float*)d_in[16];
    const float* bb    = (const float*)d_in[17];
    const float* emb   = (const float*)d_in[18];
    const float* slog  = (const float*)d_in[19];
    const float* hw    = (const float*)d_in[20];
    const float* Wout  = (const float*)d_in[21];
    const float* bout  = (const float*)d_in[22];

    float* W = (float*)d_ws;
    float* qs    = W;                  // 512*192
    float* ks    = qs + 98304;         // 512*192
    float* vs    = ks + 98304;         // 512*192
    float* qg    = vs + 98304;         // 512*144
    float* kg    = qg + 73728;         // 512*144
    float* vg    = kg + 73728;         // 512*288
    float* bias  = vg + 147456;        // 512*12*512  (reused as attn in-place)
    float* feats = bias + 3145728;     // 512*2112
    float* raw_g = feats + 1081344;    // 512*576
    // total: ~5.1M floats = 20.5 MB

    k_proj<<<dim3(32, 18), 256, 0, stream>>>(s, Wq, bq, Wk, bk, Wv, bv,
                                             Wqp, bqp, Wkp, bkp, Wvp, bvp,
                                             qs, ks, vs, raw_g);
    k_frame<<<1152, 256, 0, stream>>>(raw_g, trans, rot, qg, kg, vg);
    k_bias<<<4096, 256, 0, stream>>>(z, Wb, bb, bias);
    k_attn<<<dim3(512, 12), 256, 0, stream>>>(qs, ks, qg, kg, trans, emb, slog, hw, bias);
    k_out<<<512, 256, 0, stream>>>(bias, vs, vg, trans, rot, feats);
    k_pairfeat<<<512, 256, 0, stream>>>(bias, z, feats);
    k_outproj<<<dim3(128, 6), 256, 0, stream>>>(feats, Wout, bout, (float*)d_out);
}

// Round 5
// 460.782 us; speedup vs baseline: 1.5551x; 1.1840x over previous
//
#include <hip/hip_runtime.h>

#define NTOK 512
#define CS 384
#define CZ 128
#define CH 16
#define HN 12
#define PQ 4
#define PV 8
#define FEAT_DIM 2112   // HN * 176
#define HSEG 176        // 16 + 24 + 8 + 128

// ---------------------------------------------------------------------------
// K1: all projections as a tiled GEMM: [512 x 384] @ [384 x 1152(concat)]
// ---------------------------------------------------------------------------
__global__ __launch_bounds__(256) void k_proj(
    const float* __restrict__ s,
    const float* __restrict__ Wq,  const float* __restrict__ bq,
    const float* __restrict__ Wk,  const float* __restrict__ bk,
    const float* __restrict__ Wv,  const float* __restrict__ bv,
    const float* __restrict__ Wqp, const float* __restrict__ bqp,
    const float* __restrict__ Wkp, const float* __restrict__ bkp,
    const float* __restrict__ Wvp, const float* __restrict__ bvp,
    float* __restrict__ qs, float* __restrict__ ks, float* __restrict__ vs,
    float* __restrict__ raw_g)
{
    __shared__ float s_l[16 * CS];   // 24 KB
    const int t  = threadIdx.x;
    const int n0 = blockIdx.x * 16;

    const float4* sg  = (const float4*)(s + (size_t)n0 * CS);
    float4*       sl4 = (float4*)s_l;
#pragma unroll
    for (int j = 0; j < 6; ++j) sl4[j * 256 + t] = sg[j * 256 + t];
    __syncthreads();

    const int col = blockIdx.y * 64 + (t & 63);
    const int tq  = t >> 6;           // wave id -> token quad (wave-uniform)

    const float *W, *bv_;
    int lc, nc;
    if (col < 192)      { W = Wq;  bv_ = bq;  lc = col;       nc = 192; }
    else if (col < 384) { W = Wk;  bv_ = bk;  lc = col - 192; nc = 192; }
    else if (col < 576) { W = Wv;  bv_ = bv;  lc = col - 384; nc = 192; }
    else if (col < 720) { W = Wqp; bv_ = bqp; lc = col - 576; nc = 144; }
    else if (col < 864) { W = Wkp; bv_ = bkp; lc = col - 720; nc = 144; }
    else                { W = Wvp; bv_ = bvp; lc = col - 864; nc = 288; }

    const float* Wp   = W + lc;
    const float* srow = s_l + tq * 4 * CS;
    float a0, a1, a2, a3;
    a0 = a1 = a2 = a3 = bv_[lc];
#pragma unroll 8
    for (int k = 0; k < CS; ++k) {
        float w = Wp[(size_t)k * nc];
        a0 += srow[k] * w;
        a1 += srow[CS + k] * w;
        a2 += srow[2 * CS + k] * w;
        a3 += srow[3 * CS + k] * w;
    }

    const int n = n0 + tq * 4;
    if (col < 576) {
        float* dst = (col < 192 ? qs : col < 384 ? ks : vs);
        dst[(size_t)(n + 0) * 192 + lc] = a0;
        dst[(size_t)(n + 1) * 192 + lc] = a1;
        dst[(size_t)(n + 2) * 192 + lc] = a2;
        dst[(size_t)(n + 3) * 192 + lc] = a3;
    } else {
        const int pc = col - 576;   // qp[0:144) kp[144:288) vp[288:576)
        raw_g[(size_t)(n + 0) * 576 + pc] = a0;
        raw_g[(size_t)(n + 1) * 576 + pc] = a1;
        raw_g[(size_t)(n + 2) * 576 + pc] = a2;
        raw_g[(size_t)(n + 3) * 576 + pc] = a3;
    }
}

// ---------------------------------------------------------------------------
// K1b: apply frame (local -> global): out_i = sum_j R[i][j] x_j + t_i
// ---------------------------------------------------------------------------
__global__ __launch_bounds__(256) void k_frame(
    const float* __restrict__ raw_g,
    const float* __restrict__ trans,
    const float* __restrict__ rot,
    float* __restrict__ qg, float* __restrict__ kg, float* __restrict__ vg)
{
    const int e = blockIdx.x * 256 + threadIdx.x;   // < 512*576
    const int n = e / 576, loc = e % 576;
    const int i = loc % 3, base = loc - i;
    const float* rp = raw_g + (size_t)n * 576 + base;
    float x0 = rp[0], x1 = rp[1], x2 = rp[2];
    const float* R = rot + (size_t)n * 9 + i * 3;
    float v = trans[(size_t)n * 3 + i] + R[0] * x0 + R[1] * x1 + R[2] * x2;
    if (loc < 144)      qg[(size_t)n * 144 + loc] = v;
    else if (loc < 288) kg[(size_t)n * 144 + loc - 144] = v;
    else                vg[(size_t)n * 288 + loc - 288] = v;
}

// ---------------------------------------------------------------------------
// K2: pair bias = z @ Wb + bb, layout bias[n][h][m]
// ---------------------------------------------------------------------------
__global__ __launch_bounds__(256) void k_bias(
    const float* __restrict__ z,
    const float* __restrict__ Wb,
    const float* __restrict__ bbv,
    float* __restrict__ bias)
{
    __shared__ float a_l[64 * 132];     // 33.8 KB, padded rows
    __shared__ float wb_l[CZ * HN];     // 6 KB, [k][h]
    __shared__ float bb_l[HN];
    const int t = threadIdx.x;
    for (int i = t; i < CZ * HN; i += 256) wb_l[i] = Wb[i];
    if (t < HN) bb_l[t] = bbv[t];

    const float4* zg = (const float4*)(z + (size_t)blockIdx.x * 64 * CZ);
#pragma unroll
    for (int j = 0; j < 8; ++j) {
        const int f4i = j * 256 + t;            // 0..2047
        const int row = f4i >> 5, c4 = f4i & 31;
        *(float4*)&a_l[row * 132 + c4 * 4] = zg[f4i];
    }
    __syncthreads();

    const int row = t & 63;
    const int hg  = t >> 6;          // wave-uniform head triple
    float acc0 = 0.f, acc1 = 0.f, acc2 = 0.f;
    const float4* ar = (const float4*)&a_l[row * 132];
    const float*  wr = wb_l + hg * 3;
#pragma unroll 8
    for (int k4 = 0; k4 < 32; ++k4) {
        float4 zv = ar[k4];
        float zs[4] = {zv.x, zv.y, zv.z, zv.w};
#pragma unroll
        for (int e = 0; e < 4; ++e) {
            const float* w = wr + (k4 * 4 + e) * HN;
            acc0 += zs[e] * w[0];
            acc1 += zs[e] * w[1];
            acc2 += zs[e] * w[2];
        }
    }
    const int grow = blockIdx.x * 64 + row;     // n*512 + m
    const int n = grow >> 9, m = grow & 511;
    const int h = hg * 3;
    bias[((size_t)n * HN + h + 0) * NTOK + m] = acc0 + bb_l[h + 0];
    bias[((size_t)n * HN + h + 1) * NTOK + m] = acc1 + bb_l[h + 1];
    bias[((size_t)n * HN + h + 2) * NTOK + m] = acc2 + bb_l[h + 2];
}

// ---------------------------------------------------------------------------
// K3: logits (scalar + point + pair bias + dist-bin + multiscale), softmax.
// ---------------------------------------------------------------------------
__global__ __launch_bounds__(256) void k_attn(
    const float* __restrict__ qs, const float* __restrict__ ks,
    const float* __restrict__ qg, const float* __restrict__ kg,
    const float* __restrict__ trans,
    const float* __restrict__ emb,
    const float* __restrict__ slog,
    const float* __restrict__ hw,
    float* __restrict__ attn)   // in: bias, out: attn
{
    const int n = blockIdx.x, h = blockIdx.y, t = threadIdx.x;
    __shared__ float ql[CH];
    __shared__ float qgl[12];
    __shared__ float tl[3];
    __shared__ float ph[3];
    __shared__ float red[8];
    if (t < CH)       ql[t] = qs[(size_t)n * 192 + h * CH + t];
    else if (t < 28)  qgl[t - 16] = qg[(size_t)n * 144 + h * 12 + (t - 16)];
    else if (t < 31)  tl[t - 28] = trans[(size_t)n * 3 + (t - 28)];
    else if (t == 31) {
        float s0 = slog[0 * HN + h], s1 = slog[1 * HN + h], s2 = slog[2 * HN + h];
        float mx = fmaxf(s0, fmaxf(s1, s2));
        float e0 = expf(s0 - mx), e1 = expf(s1 - mx), e2 = expf(s2 - mx);
        float inv = 1.f / (e0 + e1 + e2);
        ph[0] = e0 * inv; ph[1] = e1 * inv; ph[2] = e2 * inv;
    }
    __syncthreads();

    const float hwv = hw[h];
    float* arow = attn + ((size_t)n * HN + h) * NTOK;
    float lg[2];
#pragma unroll
    for (int r = 0; r < 2; ++r) {
        const int m = t + r * 256;
        // scalar logits
        const float4* kp4 = (const float4*)(ks + (size_t)m * 192 + h * CH);
        const float4* ql4 = (const float4*)ql;
        float sc = 0.f;
#pragma unroll
        for (int c = 0; c < 4; ++c) {
            float4 kv = kp4[c], qv = ql4[c];
            sc += qv.x * kv.x + qv.y * kv.y + qv.z * kv.z + qv.w * kv.w;
        }
        sc *= 0.25f;  // 1/sqrt(C_H)
        // point logits
        const float4* kg4 = (const float4*)(kg + (size_t)m * 144 + h * 12);
        const float4* qg4 = (const float4*)qgl;
        float sd = 0.f;
#pragma unroll
        for (int u = 0; u < 3; ++u) {
            float4 kv = kg4[u], qv = qg4[u];
            float d0 = qv.x - kv.x, d1 = qv.y - kv.y, d2 = qv.z - kv.z, d3 = qv.w - kv.w;
            sd += d0 * d0 + d1 * d1 + d2 * d2 + d3 * d3;
        }
        float pl = -0.5f * sd * hwv;
        // pair distance -> bin + multiscale
        float dx = tl[0] - trans[(size_t)m * 3 + 0];
        float dy = tl[1] - trans[(size_t)m * 3 + 1];
        float dz = tl[2] - trans[(size_t)m * 3 + 2];
        float dist = sqrtf(dx * dx + dy * dy + dz * dz);
        int bin = (int)ceilf(dist * 2.f) - 1;
        bin = min(63, max(0, bin));
        float db = emb[bin * HN + h];
        float ms = ph[2] + (dist <= 5.f ? ph[0] : 0.f) + ((dist > 5.f && dist <= 15.f) ? ph[1] : 0.f);
        lg[r] = sc + pl + arow[m] + db + ms;
    }

    // block softmax over 512
    float mx = fmaxf(lg[0], lg[1]);
    for (int off = 32; off; off >>= 1) mx = fmaxf(mx, __shfl_down(mx, off));
    if ((t & 63) == 0) red[t >> 6] = mx;
    __syncthreads();
    if (t == 0) red[4] = fmaxf(fmaxf(red[0], red[1]), fmaxf(red[2], red[3]));
    __syncthreads();
    mx = red[4];
    float e0 = expf(lg[0] - mx), e1 = expf(lg[1] - mx);
    float sm = e0 + e1;
    for (int off = 32; off; off >>= 1) sm += __shfl_down(sm, off);
    if ((t & 63) == 0) red[t >> 6] = sm;
    __syncthreads();
    if (t == 0) red[5] = red[0] + red[1] + red[2] + red[3];
    __syncthreads();
    const float inv = 1.f / red[5];
    arow[t] = e0 * inv;
    arow[t + 256] = e1 * inv;
}

// ---------------------------------------------------------------------------
// K4a: partial out_scalar + out_pts_g over an m-chunk of 128.
// grid (512 n, 4 m-chunks); atomicAdd into sums_g[n][480] (zero-initialized).
// ---------------------------------------------------------------------------
__global__ __launch_bounds__(256) void k_out_partial(
    const float* __restrict__ attn,
    const float* __restrict__ vs, const float* __restrict__ vg,
    float* __restrict__ sums_g)
{
    __shared__ float a_l[HN * 128];    // 6 KB
    const int n = blockIdx.x, mc = blockIdx.y, t = threadIdx.x;
    for (int i = t; i < HN * 128; i += 256) {
        const int h = i >> 7, mm = i & 127;
        a_l[i] = attn[((size_t)n * HN + h) * NTOK + mc * 128 + mm];
    }
    __syncthreads();

    const int mbase = mc * 128;
    const int o0 = t;
    const int o1raw = t + 256;
    const bool act1 = o1raw < 480;
    const int o1 = act1 ? o1raw : 0;
    const int h0 = o0 / 40, j0 = o0 % 40;
    const int h1 = o1 / 40, j1 = o1 % 40;
    const float* b0; int st0;
    if (j0 < 16) { b0 = vs + h0 * 16 + j0;        st0 = 192; }
    else         { b0 = vg + h0 * 24 + (j0 - 16); st0 = 288; }
    const float* b1; int st1;
    if (j1 < 16) { b1 = vs + h1 * 16 + j1;        st1 = 192; }
    else         { b1 = vg + h1 * 24 + (j1 - 16); st1 = 288; }
    b0 += (size_t)mbase * st0;
    b1 += (size_t)mbase * st1;
    const float* a0 = a_l + h0 * 128;
    const float* a1 = a_l + h1 * 128;
    float acc0 = 0.f, acc1 = 0.f;
#pragma unroll 8
    for (int m = 0; m < 128; ++m) {
        acc0 += a0[m] * b0[(size_t)m * st0];
        acc1 += a1[m] * b1[(size_t)m * st1];
    }
    atomicAdd(&sums_g[(size_t)n * 480 + o0], acc0);
    if (act1) atomicAdd(&sums_g[(size_t)n * 480 + o1raw], acc1);
}

// ---------------------------------------------------------------------------
// K4b: epilogue — scalar copy, R^T(x - t), norms -> feats
// ---------------------------------------------------------------------------
__global__ __launch_bounds__(256) void k_out_epi(
    const float* __restrict__ sums_g,
    const float* __restrict__ trans,
    const float* __restrict__ rot,
    float* __restrict__ feats)
{
    __shared__ float sums[480];
    __shared__ float Rl[9];
    __shared__ float tl[3];
    const int n = blockIdx.x, t = threadIdx.x;
    for (int i = t; i < 480; i += 256) sums[i] = sums_g[(size_t)n * 480 + i];
    if (t < 9)       Rl[t] = rot[(size_t)n * 9 + t];
    else if (t < 12) tl[t - 9] = trans[(size_t)n * 3 + (t - 9)];
    __syncthreads();

    for (int f = t; f < 576; f += 256) {
        const int h = f / 48, j = f % 48;
        float* fp = feats + (size_t)n * FEAT_DIM + h * HSEG;
        const float* sh = sums + h * 40;
        if (j < 16) {
            fp[j] = sh[j];
        } else if (j < 40) {
            int jj = j - 16, p = jj / 3, i = jj % 3;
            float val = 0.f;
#pragma unroll
            for (int q = 0; q < 3; ++q) val += Rl[q * 3 + i] * (sh[16 + p * 3 + q] - tl[q]);
            fp[16 + jj] = val;
        } else {
            int p = j - 40;
            float s2 = 0.f;
#pragma unroll
            for (int i = 0; i < 3; ++i) {
                float val = 0.f;
#pragma unroll
                for (int q = 0; q < 3; ++q) val += Rl[q * 3 + i] * (sh[16 + p * 3 + q] - tl[q]);
                s2 += val * val;
            }
            fp[40 + p] = sqrtf(s2);
        }
    }
}

// ---------------------------------------------------------------------------
// K5: pair_feat = attn^T @ z[n]  -> feats[..., 48:176]
// ---------------------------------------------------------------------------
__global__ __launch_bounds__(256) void k_pairfeat(
    const float* __restrict__ attn,
    const float* __restrict__ z,
    float* __restrict__ feats)
{
    __shared__ float a_l[HN * NTOK];   // 24 KB
    const int n = blockIdx.x, t = threadIdx.x;
    for (int i = t; i < HN * NTOK; i += 256) a_l[i] = attn[(size_t)n * HN * NTOK + i];
    __syncthreads();

    const int c2 = (t & 63) * 2;
    const int hb = (t >> 6) * 3;
    float acc[3][2] = {{0.f, 0.f}, {0.f, 0.f}, {0.f, 0.f}};
    const float* zp = z + (size_t)n * NTOK * CZ + c2;
    const float* ap = a_l + hb * NTOK;
#pragma unroll 4
    for (int m = 0; m < NTOK; ++m) {
        float2 zv = *(const float2*)(zp + (size_t)m * CZ);
#pragma unroll
        for (int u = 0; u < 3; ++u) {
            float a = ap[u * NTOK + m];
            acc[u][0] += a * zv.x;
            acc[u][1] += a * zv.y;
        }
    }
#pragma unroll
    for (int u = 0; u < 3; ++u) {
        float2 r = make_float2(acc[u][0], acc[u][1]);
        *(float2*)&feats[(size_t)n * FEAT_DIM + (hb + u) * HSEG + 48 + c2] = r;
    }
}

// ---------------------------------------------------------------------------
// K6: out = feats @ Wout + bout  (f32, tiled K-split GEMM)
// grid (8 n-tiles x64, 6 j-tiles x64, 12 K-chunks x176); block 256.
// LDS 16-deep A(transposed)/B tiles; 4x4 acc per thread; atomicAdd epilogue
// into zero-initialized out; bout added by the bz==0 chunk.
// ---------------------------------------------------------------------------
#define KT 16
__global__ __launch_bounds__(256) void k_outproj(
    const float* __restrict__ feats,
    const float* __restrict__ Wout,
    const float* __restrict__ bout,
    float* __restrict__ out)
{
    __shared__ float As[KT][64];   // As[k][row]
    __shared__ float Bs[KT][64];   // Bs[k][col]
    const int t  = threadIdx.x;
    const int n0 = blockIdx.x * 64;
    const int j0 = blockIdx.y * 64;
    const int k0 = blockIdx.z * HSEG;

    const int arow = t >> 2, akq = (t & 3) * 4;      // A: row, k-quad
    const int bkk  = t >> 4, bjq = (t & 15) * 4;     // B: k, col-quad
    const int tr   = t >> 4, tc  = t & 15;           // C: 4x4 tile coords

    float acc[4][4] = {{0.f}};
    for (int s = 0; s < 11; ++s) {
        const int ks = k0 + s * KT;
        float4 a4 = *(const float4*)&feats[(size_t)(n0 + arow) * FEAT_DIM + ks + akq];
        float4 b4 = *(const float4*)&Wout[(size_t)(ks + bkk) * 384 + j0 + bjq];
        __syncthreads();   // previous step's LDS reads complete
        As[akq + 0][arow] = a4.x;
        As[akq + 1][arow] = a4.y;
        As[akq + 2][arow] = a4.z;
        As[akq + 3][arow] = a4.w;
        *(float4*)&Bs[bkk][bjq] = b4;
        __syncthreads();
#pragma unroll
        for (int kk = 0; kk < KT; ++kk) {
            float4 av = *(const float4*)&As[kk][tr * 4];
            float4 bv = *(const float4*)&Bs[kk][tc * 4];
            acc[0][0] += av.x * bv.x; acc[0][1] += av.x * bv.y;
            acc[0][2] += av.x * bv.z; acc[0][3] += av.x * bv.w;
            acc[1][0] += av.y * bv.x; acc[1][1] += av.y * bv.y;
            acc[1][2] += av.y * bv.z; acc[1][3] += av.y * bv.w;
            acc[2][0] += av.z * bv.x; acc[2][1] += av.z * bv.y;
            acc[2][2] += av.z * bv.z; acc[2][3] += av.z * bv.w;
            acc[3][0] += av.w * bv.x; acc[3][1] += av.w * bv.y;
            acc[3][2] += av.w * bv.z; acc[3][3] += av.w * bv.w;
        }
    }

    const bool addb = (blockIdx.z == 0);
#pragma unroll
    for (int i = 0; i < 4; ++i) {
        const int row = n0 + tr * 4 + i;
#pragma unroll
        for (int jj = 0; jj < 4; ++jj) {
            const int col = j0 + tc * 4 + jj;
            float v = acc[i][jj];
            if (addb) v += bout[col];
            atomicAdd(&out[(size_t)row * 384 + col], v);
        }
    }
}

// ---------------------------------------------------------------------------
extern "C" void kernel_launch(void* const* d_in, const int* in_sizes, int n_in,
                              void* d_out, int out_size, void* d_ws, size_t ws_size,
                              hipStream_t stream) {
    const float* s     = (const float*)d_in[0];
    const float* z     = (const float*)d_in[1];
    const float* trans = (const float*)d_in[2];
    const float* rot   = (const float*)d_in[3];
    const float* Wq    = (const float*)d_in[4];
    const float* bq    = (const float*)d_in[5];
    const float* Wk    = (const float*)d_in[6];
    const float* bk    = (const float*)d_in[7];
    const float* Wv    = (const float*)d_in[8];
    const float* bv    = (const float*)d_in[9];
    const float* Wqp   = (const float*)d_in[10];
    const float* bqp   = (const float*)d_in[11];
    const float* Wkp   = (const float*)d_in[12];
    const float* bkp   = (const float*)d_in[13];
    const float* Wvp   = (const float*)d_in[14];
    const float* bvp   = (const float*)d_in[15];
    const float* Wb    = (const float*)d_in[16];
    const float* bb    = (const float*)d_in[17];
    const float* emb   = (const float*)d_in[18];
    const float* slog  = (const float*)d_in[19];
    const float* hw    = (const float*)d_in[20];
    const float* Wout  = (const float*)d_in[21];
    const float* bout  = (const float*)d_in[22];

    float* W = (float*)d_ws;
    float* qs    = W;                  // 512*192
    float* ks    = qs + 98304;         // 512*192
    float* vs    = ks + 98304;         // 512*192
    float* qg    = vs + 98304;         // 512*144
    float* kg    = qg + 73728;         // 512*144
    float* vg    = kg + 73728;         // 512*288
    float* bias  = vg + 147456;        // 512*12*512  (reused as attn in-place)
    float* feats = bias + 3145728;     // 512*2112
    float* raw_g = feats + 1081344;    // 512*576 (reused as sums_g after k_frame)
    float* sums_g = raw_g;             // 512*480 <= 512*576
    // total: ~5.1M floats = 20.5 MB

    k_proj<<<dim3(32, 18), 256, 0, stream>>>(s, Wq, bq, Wk, bk, Wv, bv,
                                             Wqp, bqp, Wkp, bkp, Wvp, bvp,
                                             qs, ks, vs, raw_g);
    k_frame<<<1152, 256, 0, stream>>>(raw_g, trans, rot, qg, kg, vg);
    hipMemsetAsync(sums_g, 0, (size_t)NTOK * 480 * sizeof(float), stream);
    k_bias<<<4096, 256, 0, stream>>>(z, Wb, bb, bias);
    k_attn<<<dim3(512, 12), 256, 0, stream>>>(qs, ks, qg, kg, trans, emb, slog, hw, bias);
    k_out_partial<<<dim3(512, 4), 256, 0, stream>>>(bias, vs, vg, sums_g);
    k_out_epi<<<512, 256, 0, stream>>>(sums_g, trans, rot, feats);
    k_pairfeat<<<512, 256, 0, stream>>>(bias, z, feats);
    hipMemsetAsync(d_out, 0, (size_t)NTOK * 384 * sizeof(float), stream);
    k_outproj<<<dim3(8, 6, 12), 256, 0, stream>>>(feats, Wout, bout, (float*)d_out);
}

// Round 6
// 415.946 us; speedup vs baseline: 1.7227x; 1.1078x over previous
//
#include <hip/hip_runtime.h>

#define NTOK 512
#define CS 384
#define CZ 128
#define CH 16
#define HN 12
#define PQ 4
#define PV 8
#define FEAT_DIM 2112   // HN * 176
#define HSEG 176        // 16 + 24 + 8 + 128

// ---------------------------------------------------------------------------
// K1: all projections as a tiled GEMM: [512 x 384] @ [384 x 1152(concat)]
// ks is written TRANSPOSED (ksT[c][m]) for k_attn's coalesced per-m reads.
// ---------------------------------------------------------------------------
__global__ __launch_bounds__(256) void k_proj(
    const float* __restrict__ s,
    const float* __restrict__ Wq,  const float* __restrict__ bq,
    const float* __restrict__ Wk,  const float* __restrict__ bk,
    const float* __restrict__ Wv,  const float* __restrict__ bv,
    const float* __restrict__ Wqp, const float* __restrict__ bqp,
    const float* __restrict__ Wkp, const float* __restrict__ bkp,
    const float* __restrict__ Wvp, const float* __restrict__ bvp,
    float* __restrict__ qs, float* __restrict__ ksT, float* __restrict__ vs,
    float* __restrict__ raw_g)
{
    __shared__ float s_l[16 * CS];   // 24 KB
    const int t  = threadIdx.x;
    const int n0 = blockIdx.x * 16;

    const float4* sg  = (const float4*)(s + (size_t)n0 * CS);
    float4*       sl4 = (float4*)s_l;
#pragma unroll
    for (int j = 0; j < 6; ++j) sl4[j * 256 + t] = sg[j * 256 + t];
    __syncthreads();

    const int col = blockIdx.y * 64 + (t & 63);
    const int tq  = t >> 6;           // wave id -> token quad (wave-uniform)

    const float *W, *bv_;
    int lc, nc;
    if (col < 192)      { W = Wq;  bv_ = bq;  lc = col;       nc = 192; }
    else if (col < 384) { W = Wk;  bv_ = bk;  lc = col - 192; nc = 192; }
    else if (col < 576) { W = Wv;  bv_ = bv;  lc = col - 384; nc = 192; }
    else if (col < 720) { W = Wqp; bv_ = bqp; lc = col - 576; nc = 144; }
    else if (col < 864) { W = Wkp; bv_ = bkp; lc = col - 720; nc = 144; }
    else                { W = Wvp; bv_ = bvp; lc = col - 864; nc = 288; }

    const float* Wp   = W + lc;
    const float* srow = s_l + tq * 4 * CS;
    float a0, a1, a2, a3;
    a0 = a1 = a2 = a3 = bv_[lc];
#pragma unroll 8
    for (int k = 0; k < CS; ++k) {
        float w = Wp[(size_t)k * nc];
        a0 += srow[k] * w;
        a1 += srow[CS + k] * w;
        a2 += srow[2 * CS + k] * w;
        a3 += srow[3 * CS + k] * w;
    }

    const int n = n0 + tq * 4;
    if (col < 192) {
        qs[(size_t)(n + 0) * 192 + lc] = a0;
        qs[(size_t)(n + 1) * 192 + lc] = a1;
        qs[(size_t)(n + 2) * 192 + lc] = a2;
        qs[(size_t)(n + 3) * 192 + lc] = a3;
    } else if (col < 384) {
        float* p = ksT + (size_t)lc * NTOK + n;   // transposed
        p[0] = a0; p[1] = a1; p[2] = a2; p[3] = a3;
    } else if (col < 576) {
        vs[(size_t)(n + 0) * 192 + lc] = a0;
        vs[(size_t)(n + 1) * 192 + lc] = a1;
        vs[(size_t)(n + 2) * 192 + lc] = a2;
        vs[(size_t)(n + 3) * 192 + lc] = a3;
    } else {
        const int pc = col - 576;   // qp[0:144) kp[144:288) vp[288:576)
        raw_g[(size_t)(n + 0) * 576 + pc] = a0;
        raw_g[(size_t)(n + 1) * 576 + pc] = a1;
        raw_g[(size_t)(n + 2) * 576 + pc] = a2;
        raw_g[(size_t)(n + 3) * 576 + pc] = a3;
    }
}

// ---------------------------------------------------------------------------
// K1b: apply frame (local -> global). kg written TRANSPOSED; also builds
// transT[3][512] in the tail blocks.
// ---------------------------------------------------------------------------
__global__ __launch_bounds__(256) void k_frame(
    const float* __restrict__ raw_g,
    const float* __restrict__ trans,
    const float* __restrict__ rot,
    float* __restrict__ qg, float* __restrict__ kgT, float* __restrict__ vg,
    float* __restrict__ transT)
{
    const int e = blockIdx.x * 256 + threadIdx.x;
    if (e < 512 * 576) {
        const int n = e / 576, loc = e % 576;
        const int i = loc % 3, base = loc - i;
        const float* rp = raw_g + (size_t)n * 576 + base;
        float x0 = rp[0], x1 = rp[1], x2 = rp[2];
        const float* R = rot + (size_t)n * 9 + i * 3;
        float v = trans[(size_t)n * 3 + i] + R[0] * x0 + R[1] * x1 + R[2] * x2;
        if (loc < 144)      qg[(size_t)n * 144 + loc] = v;
        else if (loc < 288) kgT[(size_t)(loc - 144) * NTOK + n] = v;   // transposed
        else                vg[(size_t)n * 288 + loc - 288] = v;
    } else {
        const int idx = e - 512 * 576;
        if (idx < 3 * NTOK) {
            const int m = idx / 3, i = idx % 3;
            transT[(size_t)i * NTOK + m] = trans[(size_t)m * 3 + i];
        }
    }
}

// ---------------------------------------------------------------------------
// K2: pair bias = z @ Wb + bb, layout bias[n][h][m]
// ---------------------------------------------------------------------------
__global__ __launch_bounds__(256) void k_bias(
    const float* __restrict__ z,
    const float* __restrict__ Wb,
    const float* __restrict__ bbv,
    float* __restrict__ bias)
{
    __shared__ float a_l[64 * 132];     // 33.8 KB, padded rows
    __shared__ float wb_l[CZ * HN];     // 6 KB, [k][h]
    __shared__ float bb_l[HN];
    const int t = threadIdx.x;
    for (int i = t; i < CZ * HN; i += 256) wb_l[i] = Wb[i];
    if (t < HN) bb_l[t] = bbv[t];

    const float4* zg = (const float4*)(z + (size_t)blockIdx.x * 64 * CZ);
#pragma unroll
    for (int j = 0; j < 8; ++j) {
        const int f4i = j * 256 + t;            // 0..2047
        const int row = f4i >> 5, c4 = f4i & 31;
        *(float4*)&a_l[row * 132 + c4 * 4] = zg[f4i];
    }
    __syncthreads();

    const int row = t & 63;
    const int hg  = t >> 6;          // wave-uniform head triple
    float acc0 = 0.f, acc1 = 0.f, acc2 = 0.f;
    const float4* ar = (const float4*)&a_l[row * 132];
    const float*  wr = wb_l + hg * 3;
#pragma unroll 8
    for (int k4 = 0; k4 < 32; ++k4) {
        float4 zv = ar[k4];
        float zs[4] = {zv.x, zv.y, zv.z, zv.w};
#pragma unroll
        for (int e = 0; e < 4; ++e) {
            const float* w = wr + (k4 * 4 + e) * HN;
            acc0 += zs[e] * w[0];
            acc1 += zs[e] * w[1];
            acc2 += zs[e] * w[2];
        }
    }
    const int grow = blockIdx.x * 64 + row;     // n*512 + m
    const int n = grow >> 9, m = grow & 511;
    const int h = hg * 3;
    bias[((size_t)n * HN + h + 0) * NTOK + m] = acc0 + bb_l[h + 0];
    bias[((size_t)n * HN + h + 1) * NTOK + m] = acc1 + bb_l[h + 1];
    bias[((size_t)n * HN + h + 2) * NTOK + m] = acc2 + bb_l[h + 2];
}

// ---------------------------------------------------------------------------
// K3: logits + softmax, all K-side reads coalesced via transposed layouts.
// block per (n,h); attn written in place over bias.
// ---------------------------------------------------------------------------
__global__ __launch_bounds__(256) void k_attn(
    const float* __restrict__ qs, const float* __restrict__ ksT,
    const float* __restrict__ qg, const float* __restrict__ kgT,
    const float* __restrict__ trans, const float* __restrict__ transT,
    const float* __restrict__ emb,
    const float* __restrict__ slog,
    const float* __restrict__ hw,
    float* __restrict__ attn)   // in: bias, out: attn
{
    const int n = blockIdx.x, h = blockIdx.y, t = threadIdx.x;
    __shared__ float ql[CH];
    __shared__ float qgl[12];
    __shared__ float tl[3];
    __shared__ float ph[3];
    __shared__ float red[8];
    __shared__ float emb_l[64];
    if (t < CH)       ql[t] = qs[(size_t)n * 192 + h * CH + t];
    else if (t < 28)  qgl[t - 16] = qg[(size_t)n * 144 + h * 12 + (t - 16)];
    else if (t < 31)  tl[t - 28] = trans[(size_t)n * 3 + (t - 28)];
    else if (t == 31) {
        float s0 = slog[0 * HN + h], s1 = slog[1 * HN + h], s2 = slog[2 * HN + h];
        float mx = fmaxf(s0, fmaxf(s1, s2));
        float e0 = expf(s0 - mx), e1 = expf(s1 - mx), e2 = expf(s2 - mx);
        float inv = 1.f / (e0 + e1 + e2);
        ph[0] = e0 * inv; ph[1] = e1 * inv; ph[2] = e2 * inv;
    } else if (t >= 64 && t < 128) {
        emb_l[t - 64] = emb[(size_t)(t - 64) * HN + h];
    }
    __syncthreads();

    const float hwv = hw[h];
    float* arow = attn + ((size_t)n * HN + h) * NTOK;
    const float* ksh = ksT + (size_t)h * CH * NTOK;
    const float* kgh = kgT + (size_t)h * 12 * NTOK;
    float lg[2];
#pragma unroll
    for (int r = 0; r < 2; ++r) {
        const int m = t + r * 256;
        float sc = 0.f;
#pragma unroll
        for (int c = 0; c < CH; ++c)
            sc += ql[c] * ksh[(size_t)c * NTOK + m];
        sc *= 0.25f;  // 1/sqrt(C_H)
        float sd = 0.f;
#pragma unroll
        for (int i = 0; i < 12; ++i) {
            float d = qgl[i] - kgh[(size_t)i * NTOK + m];
            sd += d * d;
        }
        float pl = -0.5f * sd * hwv;
        float dx = tl[0] - transT[m];
        float dy = tl[1] - transT[NTOK + m];
        float dz = tl[2] - transT[2 * NTOK + m];
        float dist = sqrtf(dx * dx + dy * dy + dz * dz);
        int bin = (int)ceilf(dist * 2.f) - 1;
        bin = min(63, max(0, bin));
        float db = emb_l[bin];
        float ms = ph[2] + (dist <= 5.f ? ph[0] : 0.f) + ((dist > 5.f && dist <= 15.f) ? ph[1] : 0.f);
        lg[r] = sc + pl + arow[m] + db + ms;
    }

    // block softmax over 512
    float mx = fmaxf(lg[0], lg[1]);
    for (int off = 32; off; off >>= 1) mx = fmaxf(mx, __shfl_down(mx, off));
    if ((t & 63) == 0) red[t >> 6] = mx;
    __syncthreads();
    if (t == 0) red[4] = fmaxf(fmaxf(red[0], red[1]), fmaxf(red[2], red[3]));
    __syncthreads();
    mx = red[4];
    float e0 = expf(lg[0] - mx), e1 = expf(lg[1] - mx);
    float sm = e0 + e1;
    for (int off = 32; off; off >>= 1) sm += __shfl_down(sm, off);
    if ((t & 63) == 0) red[t >> 6] = sm;
    __syncthreads();
    if (t == 0) red[5] = red[0] + red[1] + red[2] + red[3];
    __syncthreads();
    const float inv = 1.f / red[5];
    arow[t] = e0 * inv;
    arow[t + 256] = e1 * inv;
}

// ---------------------------------------------------------------------------
// K4: out_scalar + out_pts_g as an LDS-tiled GEMM per (n-tile 64, h), with
// the global->local + norm epilogue fused. 4 waves each own a quarter of m;
// register tile 4n x 10j per lane; slab partials merged in LDS.
// ---------------------------------------------------------------------------
__global__ __launch_bounds__(256) void k_outmm(
    const float* __restrict__ attn,
    const float* __restrict__ vs, const float* __restrict__ vg,
    const float* __restrict__ trans,
    const float* __restrict__ rot,
    float* __restrict__ feats)
{
    __shared__ float As_t[64][65];     // [m][n], +1 pad (16.6 KB)
    __shared__ float Vs[64][40];       // [m][j]  (10.2 KB)
    __shared__ float out_l[64 * 40];   // merged sums (10 KB)
    __shared__ float Rl[64][9];
    __shared__ float tl[64][3];
    const int t   = threadIdx.x;
    const int gn0 = blockIdx.x * 64;
    const int h   = blockIdx.y;

    const int slab  = t >> 6;          // wave id -> m quarter
    const int w     = t & 63;
    const int n0l   = (w >> 2) * 4;    // 16 n-groups of 4
    const int j0    = (w & 3) * 10;    // 4 j-groups of 10

    float acc[4][10];
#pragma unroll
    for (int i = 0; i < 4; ++i)
#pragma unroll
        for (int k = 0; k < 10; ++k) acc[i][k] = 0.f;

    for (int step = 0; step < 8; ++step) {
        const int mb = step * 64;
        __syncthreads();
        // stage A^T: 4096 floats
#pragma unroll
        for (int jj = 0; jj < 4; ++jj) {
            const int f = t + jj * 256;            // float4 index 0..1023
            const int n_loc = f >> 4, c4 = f & 15;
            float4 a = *(const float4*)&attn[(((size_t)(gn0 + n_loc)) * HN + h) * NTOK + mb + c4 * 4];
            As_t[c4 * 4 + 0][n_loc] = a.x;
            As_t[c4 * 4 + 1][n_loc] = a.y;
            As_t[c4 * 4 + 2][n_loc] = a.z;
            As_t[c4 * 4 + 3][n_loc] = a.w;
        }
        // stage V chunk: 2560 floats
#pragma unroll
        for (int jj = 0; jj < 10; ++jj) {
            const int f = t + jj * 256;
            const int m_loc = f / 40, jv = f % 40;
            float v;
            if (jv < 16) v = vs[(size_t)(mb + m_loc) * 192 + h * 16 + jv];
            else         v = vg[(size_t)(mb + m_loc) * 288 + h * 24 + (jv - 16)];
            Vs[m_loc][jv] = v;
        }
        __syncthreads();
        // compute over this wave's m quarter
#pragma unroll
        for (int mi = 0; mi < 16; ++mi) {
            const int m = slab * 16 + mi;
            float4 a  = *(const float4*)&As_t[m][n0l];
            float2 v0 = *(const float2*)&Vs[m][j0 + 0];
            float2 v1 = *(const float2*)&Vs[m][j0 + 2];
            float2 v2 = *(const float2*)&Vs[m][j0 + 4];
            float2 v3 = *(const float2*)&Vs[m][j0 + 6];
            float2 v4 = *(const float2*)&Vs[m][j0 + 8];
            const float av[4]  = {a.x, a.y, a.z, a.w};
            const float vv[10] = {v0.x, v0.y, v1.x, v1.y, v2.x,
                                  v2.y, v3.x, v3.y, v4.x, v4.y};
#pragma unroll
            for (int i = 0; i < 4; ++i)
#pragma unroll
                for (int k = 0; k < 10; ++k)
                    acc[i][k] += av[i] * vv[k];
        }
    }

    // merge the 4 slabs into out_l
    for (int s = 0; s < 4; ++s) {
        __syncthreads();
        if (slab == s) {
#pragma unroll
            for (int i = 0; i < 4; ++i)
#pragma unroll
                for (int k = 0; k < 10; ++k) {
                    float* p = &out_l[(n0l + i) * 40 + j0 + k];
                    if (s == 0) *p = acc[i][k];
                    else        *p += acc[i][k];
                }
        }
    }
    // stage frames
    for (int i = t; i < 64 * 12; i += 256) {
        const int n_loc = i / 12, r = i % 12;
        if (r < 9) Rl[n_loc][r] = rot[(size_t)(gn0 + n_loc) * 9 + r];
        else       tl[n_loc][r - 9] = trans[(size_t)(gn0 + n_loc) * 3 + (r - 9)];
    }
    __syncthreads();

    // epilogue: 64 n x 48 outputs (16 scalar, 24 local pts, 8 norms)
    for (int f = t; f < 64 * 48; f += 256) {
        const int n_loc = f / 48, j = f % 48;
        const float* sh = &out_l[n_loc * 40];
        float* fp = feats + (size_t)(gn0 + n_loc) * FEAT_DIM + h * HSEG;
        const float* R = Rl[n_loc];
        const float* tv = tl[n_loc];
        if (j < 16) {
            fp[j] = sh[j];
        } else if (j < 40) {
            const int jj = j - 16, p = jj / 3, i = jj % 3;
            float val = 0.f;
#pragma unroll
            for (int q = 0; q < 3; ++q) val += R[q * 3 + i] * (sh[16 + p * 3 + q] - tv[q]);
            fp[16 + jj] = val;
        } else {
            const int p = j - 40;
            float s2 = 0.f;
#pragma unroll
            for (int i = 0; i < 3; ++i) {
                float val = 0.f;
#pragma unroll
                for (int q = 0; q < 3; ++q) val += R[q * 3 + i] * (sh[16 + p * 3 + q] - tv[q]);
                s2 += val * val;
            }
            fp[40 + p] = sqrtf(s2);
        }
    }
}

// ---------------------------------------------------------------------------
// K5: pair_feat = attn^T @ z[n]  -> feats[..., 48:176]
// ---------------------------------------------------------------------------
__global__ __launch_bounds__(256) void k_pairfeat(
    const float* __restrict__ attn,
    const float* __restrict__ z,
    float* __restrict__ feats)
{
    __shared__ float a_l[HN * NTOK];   // 24 KB
    const int n = blockIdx.x, t = threadIdx.x;
    for (int i = t; i < HN * NTOK; i += 256) a_l[i] = attn[(size_t)n * HN * NTOK + i];
    __syncthreads();

    const int c2 = (t & 63) * 2;
    const int hb = (t >> 6) * 3;
    float acc[3][2] = {{0.f, 0.f}, {0.f, 0.f}, {0.f, 0.f}};
    const float* zp = z + (size_t)n * NTOK * CZ + c2;
    const float* ap = a_l + hb * NTOK;
#pragma unroll 8
    for (int m = 0; m < NTOK; ++m) {
        float2 zv = *(const float2*)(zp + (size_t)m * CZ);
#pragma unroll
        for (int u = 0; u < 3; ++u) {
            float a = ap[u * NTOK + m];
            acc[u][0] += a * zv.x;
            acc[u][1] += a * zv.y;
        }
    }
#pragma unroll
    for (int u = 0; u < 3; ++u) {
        float2 r = make_float2(acc[u][0], acc[u][1]);
        *(float2*)&feats[(size_t)n * FEAT_DIM + (hb + u) * HSEG + 48 + c2] = r;
    }
}

// ---------------------------------------------------------------------------
// K6: out = feats @ Wout + bout  (f32, tiled K-split GEMM, atomic epilogue)
// ---------------------------------------------------------------------------
#define KT 16
__global__ __launch_bounds__(256) void k_outproj(
    const float* __restrict__ feats,
    const float* __restrict__ Wout,
    const float* __restrict__ bout,
    float* __restrict__ out)
{
    __shared__ float As[KT][64];   // As[k][row]
    __shared__ float Bs[KT][64];   // Bs[k][col]
    const int t  = threadIdx.x;
    const int n0 = blockIdx.x * 64;
    const int j0 = blockIdx.y * 64;
    const int k0 = blockIdx.z * HSEG;

    const int arow = t >> 2, akq = (t & 3) * 4;      // A: row, k-quad
    const int bkk  = t >> 4, bjq = (t & 15) * 4;     // B: k, col-quad
    const int tr   = t >> 4, tc  = t & 15;           // C: 4x4 tile coords

    float acc[4][4] = {{0.f}};
    for (int s = 0; s < 11; ++s) {
        const int ks = k0 + s * KT;
        float4 a4 = *(const float4*)&feats[(size_t)(n0 + arow) * FEAT_DIM + ks + akq];
        float4 b4 = *(const float4*)&Wout[(size_t)(ks + bkk) * 384 + j0 + bjq];
        __syncthreads();   // previous step's LDS reads complete
        As[akq + 0][arow] = a4.x;
        As[akq + 1][arow] = a4.y;
        As[akq + 2][arow] = a4.z;
        As[akq + 3][arow] = a4.w;
        *(float4*)&Bs[bkk][bjq] = b4;
        __syncthreads();
#pragma unroll
        for (int kk = 0; kk < KT; ++kk) {
            float4 av = *(const float4*)&As[kk][tr * 4];
            float4 bv = *(const float4*)&Bs[kk][tc * 4];
            acc[0][0] += av.x * bv.x; acc[0][1] += av.x * bv.y;
            acc[0][2] += av.x * bv.z; acc[0][3] += av.x * bv.w;
            acc[1][0] += av.y * bv.x; acc[1][1] += av.y * bv.y;
            acc[1][2] += av.y * bv.z; acc[1][3] += av.y * bv.w;
            acc[2][0] += av.z * bv.x; acc[2][1] += av.z * bv.y;
            acc[2][2] += av.z * bv.z; acc[2][3] += av.z * bv.w;
            acc[3][0] += av.w * bv.x; acc[3][1] += av.w * bv.y;
            acc[3][2] += av.w * bv.z; acc[3][3] += av.w * bv.w;
        }
    }

    const bool addb = (blockIdx.z == 0);
#pragma unroll
    for (int i = 0; i < 4; ++i) {
        const int row = n0 + tr * 4 + i;
#pragma unroll
        for (int jj = 0; jj < 4; ++jj) {
            const int col = j0 + tc * 4 + jj;
            float v = acc[i][jj];
            if (addb) v += bout[col];
            atomicAdd(&out[(size_t)row * 384 + col], v);
        }
    }
}

// ---------------------------------------------------------------------------
extern "C" void kernel_launch(void* const* d_in, const int* in_sizes, int n_in,
                              void* d_out, int out_size, void* d_ws, size_t ws_size,
                              hipStream_t stream) {
    const float* s     = (const float*)d_in[0];
    const float* z     = (const float*)d_in[1];
    const float* trans = (const float*)d_in[2];
    const float* rot   = (const float*)d_in[3];
    const float* Wq    = (const float*)d_in[4];
    const float* bq    = (const float*)d_in[5];
    const float* Wk    = (const float*)d_in[6];
    const float* bk    = (const float*)d_in[7];
    const float* Wv    = (const float*)d_in[8];
    const float* bv    = (const float*)d_in[9];
    const float* Wqp   = (const float*)d_in[10];
    const float* bqp   = (const float*)d_in[11];
    const float* Wkp   = (const float*)d_in[12];
    const float* bkp   = (const float*)d_in[13];
    const float* Wvp   = (const float*)d_in[14];
    const float* bvp   = (const float*)d_in[15];
    const float* Wb    = (const float*)d_in[16];
    const float* bb    = (const float*)d_in[17];
    const float* emb   = (const float*)d_in[18];
    const float* slog  = (const float*)d_in[19];
    const float* hw    = (const float*)d_in[20];
    const float* Wout  = (const float*)d_in[21];
    const float* bout  = (const float*)d_in[22];

    float* W = (float*)d_ws;
    float* qs     = W;                    // 512*192
    float* ksT    = qs + 98304;           // 192*512 (transposed)
    float* vs     = ksT + 98304;          // 512*192
    float* qg     = vs + 98304;           // 512*144
    float* kgT    = qg + 73728;           // 144*512 (transposed)
    float* vg     = kgT + 73728;          // 512*288
    float* transT = vg + 147456;          // 3*512
    float* bias   = transT + 1536;        // 512*12*512 (reused as attn)
    float* feats  = bias + 3145728;       // 512*2112
    float* raw_g  = feats + 1081344;      // 512*576
    // total: ~5.11M floats = 20.5 MB

    k_proj<<<dim3(32, 18), 256, 0, stream>>>(s, Wq, bq, Wk, bk, Wv, bv,
                                             Wqp, bqp, Wkp, bkp, Wvp, bvp,
                                             qs, ksT, vs, raw_g);
    k_frame<<<1158, 256, 0, stream>>>(raw_g, trans, rot, qg, kgT, vg, transT);
    k_bias<<<4096, 256, 0, stream>>>(z, Wb, bb, bias);
    k_attn<<<dim3(512, 12), 256, 0, stream>>>(qs, ksT, qg, kgT, trans, transT,
                                              emb, slog, hw, bias);
    k_outmm<<<dim3(8, 12), 256, 0, stream>>>(bias, vs, vg, trans, rot, feats);
    k_pairfeat<<<512, 256, 0, stream>>>(bias, z, feats);
    hipMemsetAsync(d_out, 0, (size_t)NTOK * 384 * sizeof(float), stream);
    k_outproj<<<dim3(8, 6, 12), 256, 0, stream>>>(feats, Wout, bout, (float*)d_out);
}

// Round 7
// 400.197 us; speedup vs baseline: 1.7905x; 1.0394x over previous
//
#include <hip/hip_runtime.h>

#define NTOK 512
#define CS 384
#define CZ 128
#define CH 16
#define HN 12
#define PQ 4
#define PV 8
#define FEAT_DIM 2112   // HN * 176
#define HSEG 176        // 16 + 24 + 8 + 128

// ---------------------------------------------------------------------------
// K1: all projections as a tiled GEMM: [512 x 384] @ [384 x 1152(concat)]
// grid (32 token-groups of 16, 18 col-groups of 64); W staged in LDS 16-deep
// tiles (prefetch before barrier) so the K-loop is LDS-only.
// ks written TRANSPOSED (ksT[c][m]) for k_attn's coalesced reads.
// ---------------------------------------------------------------------------
__global__ __launch_bounds__(256) void k_proj(
    const float* __restrict__ s,
    const float* __restrict__ Wq,  const float* __restrict__ bq,
    const float* __restrict__ Wk,  const float* __restrict__ bk,
    const float* __restrict__ Wv,  const float* __restrict__ bv,
    const float* __restrict__ Wqp, const float* __restrict__ bqp,
    const float* __restrict__ Wkp, const float* __restrict__ bkp,
    const float* __restrict__ Wvp, const float* __restrict__ bvp,
    float* __restrict__ qs, float* __restrict__ ksT, float* __restrict__ vs,
    float* __restrict__ raw_g)
{
    __shared__ float s_l[16 * CS];   // 24 KB
    __shared__ float Ws[16][64];     // 4 KB
    const int t  = threadIdx.x;
    const int n0 = blockIdx.x * 16;

    const float4* sg  = (const float4*)(s + (size_t)n0 * CS);
    float4*       sl4 = (float4*)s_l;
#pragma unroll
    for (int j = 0; j < 6; ++j) sl4[j * 256 + t] = sg[j * 256 + t];

    // compute lane's column + bias
    const int col = blockIdx.y * 64 + (t & 63);
    const int tq  = t >> 6;           // wave id -> token quad (wave-uniform)
    const float* bv_;
    int lc;
    if (col < 192)      { bv_ = bq;  lc = col;       }
    else if (col < 384) { bv_ = bk;  lc = col - 192; }
    else if (col < 576) { bv_ = bv;  lc = col - 384; }
    else if (col < 720) { bv_ = bqp; lc = col - 576; }
    else if (col < 864) { bv_ = bkp; lc = col - 720; }
    else                { bv_ = bvp; lc = col - 864; }

    // staging thread's column quad (segment boundaries are %4 == 0)
    const int kk_s = t >> 4, cq = t & 15;
    const int gcol = blockIdx.y * 64 + cq * 4;
    const float* Wsrc; int lcs, ncs;
    if (gcol < 192)      { Wsrc = Wq;  lcs = gcol;       ncs = 192; }
    else if (gcol < 384) { Wsrc = Wk;  lcs = gcol - 192; ncs = 192; }
    else if (gcol < 576) { Wsrc = Wv;  lcs = gcol - 384; ncs = 192; }
    else if (gcol < 720) { Wsrc = Wqp; lcs = gcol - 576; ncs = 144; }
    else if (gcol < 864) { Wsrc = Wkp; lcs = gcol - 720; ncs = 144; }
    else                 { Wsrc = Wvp; lcs = gcol - 864; ncs = 288; }

    float a0, a1, a2, a3;
    a0 = a1 = a2 = a3 = bv_[lc];
    __syncthreads();   // s_l ready

    for (int ks = 0; ks < CS; ks += 16) {
        float4 w4 = *(const float4*)&Wsrc[(size_t)(ks + kk_s) * ncs + lcs];
        __syncthreads();   // previous step's Ws reads done
        *(float4*)&Ws[kk_s][cq * 4] = w4;
        __syncthreads();
        const float* srow = s_l + tq * 4 * CS + ks;
#pragma unroll
        for (int kk = 0; kk < 16; ++kk) {
            float w = Ws[kk][t & 63];
            a0 += srow[kk] * w;
            a1 += srow[CS + kk] * w;
            a2 += srow[2 * CS + kk] * w;
            a3 += srow[3 * CS + kk] * w;
        }
    }

    const int n = n0 + tq * 4;
    if (col < 192) {
        qs[(size_t)(n + 0) * 192 + lc] = a0;
        qs[(size_t)(n + 1) * 192 + lc] = a1;
        qs[(size_t)(n + 2) * 192 + lc] = a2;
        qs[(size_t)(n + 3) * 192 + lc] = a3;
    } else if (col < 384) {
        float* p = ksT + (size_t)lc * NTOK + n;   // transposed
        p[0] = a0; p[1] = a1; p[2] = a2; p[3] = a3;
    } else if (col < 576) {
        vs[(size_t)(n + 0) * 192 + lc] = a0;
        vs[(size_t)(n + 1) * 192 + lc] = a1;
        vs[(size_t)(n + 2) * 192 + lc] = a2;
        vs[(size_t)(n + 3) * 192 + lc] = a3;
    } else {
        const int pc = col - 576;   // qp[0:144) kp[144:288) vp[288:576)
        raw_g[(size_t)(n + 0) * 576 + pc] = a0;
        raw_g[(size_t)(n + 1) * 576 + pc] = a1;
        raw_g[(size_t)(n + 2) * 576 + pc] = a2;
        raw_g[(size_t)(n + 3) * 576 + pc] = a3;
    }
}

// ---------------------------------------------------------------------------
// K1b: apply frame (local -> global). kg written TRANSPOSED; also builds
// transT[3][512] in the tail blocks.
// ---------------------------------------------------------------------------
__global__ __launch_bounds__(256) void k_frame(
    const float* __restrict__ raw_g,
    const float* __restrict__ trans,
    const float* __restrict__ rot,
    float* __restrict__ qg, float* __restrict__ kgT, float* __restrict__ vg,
    float* __restrict__ transT)
{
    const int e = blockIdx.x * 256 + threadIdx.x;
    if (e < 512 * 576) {
        const int n = e / 576, loc = e % 576;
        const int i = loc % 3, base = loc - i;
        const float* rp = raw_g + (size_t)n * 576 + base;
        float x0 = rp[0], x1 = rp[1], x2 = rp[2];
        const float* R = rot + (size_t)n * 9 + i * 3;
        float v = trans[(size_t)n * 3 + i] + R[0] * x0 + R[1] * x1 + R[2] * x2;
        if (loc < 144)      qg[(size_t)n * 144 + loc] = v;
        else if (loc < 288) kgT[(size_t)(loc - 144) * NTOK + n] = v;   // transposed
        else                vg[(size_t)n * 288 + loc - 288] = v;
    } else {
        const int idx = e - 512 * 576;
        if (idx < 3 * NTOK) {
            const int m = idx / 3, i = idx % 3;
            transT[(size_t)i * NTOK + m] = trans[(size_t)m * 3 + i];
        }
    }
}

// ---------------------------------------------------------------------------
// K2: pair bias = z @ Wb + bb, layout bias[n][h][m]
// LDS row stride 133 (gcd(5,32)=1) -> conflict-free scalar compute reads.
// ---------------------------------------------------------------------------
__global__ __launch_bounds__(256) void k_bias(
    const float* __restrict__ z,
    const float* __restrict__ Wb,
    const float* __restrict__ bbv,
    float* __restrict__ bias)
{
    __shared__ float a_l[64 * 133];     // 34 KB, stride-133 rows
    __shared__ float wb_l[CZ * HN];     // 6 KB, [k][h]
    __shared__ float bb_l[HN];
    const int t = threadIdx.x;
    for (int i = t; i < CZ * HN; i += 256) wb_l[i] = Wb[i];
    if (t < HN) bb_l[t] = bbv[t];

    const float4* zg = (const float4*)(z + (size_t)blockIdx.x * 64 * CZ);
#pragma unroll
    for (int j = 0; j < 8; ++j) {
        const int f4i = j * 256 + t;            // 0..2047
        const int row = f4i >> 5, c4 = f4i & 31;
        float4 v = zg[f4i];
        float* dst = &a_l[row * 133 + c4 * 4];
        dst[0] = v.x; dst[1] = v.y; dst[2] = v.z; dst[3] = v.w;
    }
    __syncthreads();

    const int row = t & 63;
    const int hg  = t >> 6;          // wave-uniform head triple
    float acc0 = 0.f, acc1 = 0.f, acc2 = 0.f;
    const float* ar = &a_l[row * 133];
    const float* wr = wb_l + hg * 3;
#pragma unroll 8
    for (int c = 0; c < CZ; ++c) {
        float zc = ar[c];
        const float* w = wr + c * HN;
        acc0 += zc * w[0];
        acc1 += zc * w[1];
        acc2 += zc * w[2];
    }
    const int grow = blockIdx.x * 64 + row;     // n*512 + m
    const int n = grow >> 9, m = grow & 511;
    const int h = hg * 3;
    bias[((size_t)n * HN + h + 0) * NTOK + m] = acc0 + bb_l[h + 0];
    bias[((size_t)n * HN + h + 1) * NTOK + m] = acc1 + bb_l[h + 1];
    bias[((size_t)n * HN + h + 2) * NTOK + m] = acc2 + bb_l[h + 2];
}

// ---------------------------------------------------------------------------
// K3: logits + softmax, all K-side reads coalesced via transposed layouts.
// ---------------------------------------------------------------------------
__global__ __launch_bounds__(256) void k_attn(
    const float* __restrict__ qs, const float* __restrict__ ksT,
    const float* __restrict__ qg, const float* __restrict__ kgT,
    const float* __restrict__ trans, const float* __restrict__ transT,
    const float* __restrict__ emb,
    const float* __restrict__ slog,
    const float* __restrict__ hw,
    float* __restrict__ attn)   // in: bias, out: attn
{
    const int n = blockIdx.x, h = blockIdx.y, t = threadIdx.x;
    __shared__ float ql[CH];
    __shared__ float qgl[12];
    __shared__ float tl[3];
    __shared__ float ph[3];
    __shared__ float red[8];
    __shared__ float emb_l[64];
    if (t < CH)       ql[t] = qs[(size_t)n * 192 + h * CH + t];
    else if (t < 28)  qgl[t - 16] = qg[(size_t)n * 144 + h * 12 + (t - 16)];
    else if (t < 31)  tl[t - 28] = trans[(size_t)n * 3 + (t - 28)];
    else if (t == 31) {
        float s0 = slog[0 * HN + h], s1 = slog[1 * HN + h], s2 = slog[2 * HN + h];
        float mx = fmaxf(s0, fmaxf(s1, s2));
        float e0 = expf(s0 - mx), e1 = expf(s1 - mx), e2 = expf(s2 - mx);
        float inv = 1.f / (e0 + e1 + e2);
        ph[0] = e0 * inv; ph[1] = e1 * inv; ph[2] = e2 * inv;
    } else if (t >= 64 && t < 128) {
        emb_l[t - 64] = emb[(size_t)(t - 64) * HN + h];
    }
    __syncthreads();

    const float hwv = hw[h];
    float* arow = attn + ((size_t)n * HN + h) * NTOK;
    const float* ksh = ksT + (size_t)h * CH * NTOK;
    const float* kgh = kgT + (size_t)h * 12 * NTOK;
    float lg[2];
#pragma unroll
    for (int r = 0; r < 2; ++r) {
        const int m = t + r * 256;
        float sc = 0.f;
#pragma unroll
        for (int c = 0; c < CH; ++c)
            sc += ql[c] * ksh[(size_t)c * NTOK + m];
        sc *= 0.25f;  // 1/sqrt(C_H)
        float sd = 0.f;
#pragma unroll
        for (int i = 0; i < 12; ++i) {
            float d = qgl[i] - kgh[(size_t)i * NTOK + m];
            sd += d * d;
        }
        float pl = -0.5f * sd * hwv;
        float dx = tl[0] - transT[m];
        float dy = tl[1] - transT[NTOK + m];
        float dz = tl[2] - transT[2 * NTOK + m];
        float dist = sqrtf(dx * dx + dy * dy + dz * dz);
        int bin = (int)ceilf(dist * 2.f) - 1;
        bin = min(63, max(0, bin));
        float db = emb_l[bin];
        float ms = ph[2] + (dist <= 5.f ? ph[0] : 0.f) + ((dist > 5.f && dist <= 15.f) ? ph[1] : 0.f);
        lg[r] = sc + pl + arow[m] + db + ms;
    }

    // block softmax over 512
    float mx = fmaxf(lg[0], lg[1]);
    for (int off = 32; off; off >>= 1) mx = fmaxf(mx, __shfl_down(mx, off));
    if ((t & 63) == 0) red[t >> 6] = mx;
    __syncthreads();
    if (t == 0) red[4] = fmaxf(fmaxf(red[0], red[1]), fmaxf(red[2], red[3]));
    __syncthreads();
    mx = red[4];
    float e0 = expf(lg[0] - mx), e1 = expf(lg[1] - mx);
    float sm = e0 + e1;
    for (int off = 32; off; off >>= 1) sm += __shfl_down(sm, off);
    if ((t & 63) == 0) red[t >> 6] = sm;
    __syncthreads();
    if (t == 0) red[5] = red[0] + red[1] + red[2] + red[3];
    __syncthreads();
    const float inv = 1.f / red[5];
    arow[t] = e0 * inv;
    arow[t + 256] = e1 * inv;
}

// ---------------------------------------------------------------------------
// K4: out_scalar + out_pts_g tiled GEMM per (n-tile 32, h); epilogue fused.
// grid (16, 12) = 192 blocks; 4 waves own m-quarters; 4n x 5j register tile.
// ---------------------------------------------------------------------------
__global__ __launch_bounds__(256) void k_outmm(
    const float* __restrict__ attn,
    const float* __restrict__ vs, const float* __restrict__ vg,
    const float* __restrict__ trans,
    const float* __restrict__ rot,
    float* __restrict__ feats)
{
    __shared__ float As_t[64][33];     // [m][n], +1 pad (8.4 KB)
    __shared__ float Vs[64][40];       // [m][j]  (10.2 KB)
    __shared__ float out_l[32 * 40];   // merged sums (5 KB)
    __shared__ float Rl[32][9];
    __shared__ float tl[32][3];
    const int t   = threadIdx.x;
    const int gn0 = blockIdx.x * 32;
    const int h   = blockIdx.y;

    const int slab  = t >> 6;          // wave id -> m quarter
    const int w     = t & 63;
    const int n0l   = (w >> 3) * 4;    // 8 n-groups of 4
    const int j0    = (w & 7) * 5;     // 8 j-groups of 5

    float acc[4][5];
#pragma unroll
    for (int i = 0; i < 4; ++i)
#pragma unroll
        for (int k = 0; k < 5; ++k) acc[i][k] = 0.f;

    for (int step = 0; step < 8; ++step) {
        const int mb = step * 64;
        __syncthreads();
        // stage A^T: 32 n x 64 m = 512 float4
#pragma unroll
        for (int jj = 0; jj < 2; ++jj) {
            const int f = t + jj * 256;
            const int n_loc = f >> 4, c4 = f & 15;
            float4 a = *(const float4*)&attn[(((size_t)(gn0 + n_loc)) * HN + h) * NTOK + mb + c4 * 4];
            As_t[c4 * 4 + 0][n_loc] = a.x;
            As_t[c4 * 4 + 1][n_loc] = a.y;
            As_t[c4 * 4 + 2][n_loc] = a.z;
            As_t[c4 * 4 + 3][n_loc] = a.w;
        }
        // stage V chunk: 2560 floats
#pragma unroll
        for (int jj = 0; jj < 10; ++jj) {
            const int f = t + jj * 256;
            const int m_loc = f / 40, jv = f % 40;
            float v;
            if (jv < 16) v = vs[(size_t)(mb + m_loc) * 192 + h * 16 + jv];
            else         v = vg[(size_t)(mb + m_loc) * 288 + h * 24 + (jv - 16)];
            Vs[m_loc][jv] = v;
        }
        __syncthreads();
#pragma unroll
        for (int mi = 0; mi < 16; ++mi) {
            const int m = slab * 16 + mi;
            float4 a = *(const float4*)&As_t[m][n0l];
            float vv[5];
#pragma unroll
            for (int k = 0; k < 5; ++k) vv[k] = Vs[m][j0 + k];
            const float av[4] = {a.x, a.y, a.z, a.w};
#pragma unroll
            for (int i = 0; i < 4; ++i)
#pragma unroll
                for (int k = 0; k < 5; ++k)
                    acc[i][k] += av[i] * vv[k];
        }
    }

    // merge the 4 slabs into out_l
    for (int s = 0; s < 4; ++s) {
        __syncthreads();
        if (slab == s) {
#pragma unroll
            for (int i = 0; i < 4; ++i)
#pragma unroll
                for (int k = 0; k < 5; ++k) {
                    float* p = &out_l[(n0l + i) * 40 + j0 + k];
                    if (s == 0) *p = acc[i][k];
                    else        *p += acc[i][k];
                }
        }
    }
    // stage frames
    for (int i = t; i < 32 * 12; i += 256) {
        const int n_loc = i / 12, r = i % 12;
        if (r < 9) Rl[n_loc][r] = rot[(size_t)(gn0 + n_loc) * 9 + r];
        else       tl[n_loc][r - 9] = trans[(size_t)(gn0 + n_loc) * 3 + (r - 9)];
    }
    __syncthreads();

    // epilogue: 32 n x 48 outputs (16 scalar, 24 local pts, 8 norms)
    for (int f = t; f < 32 * 48; f += 256) {
        const int n_loc = f / 48, j = f % 48;
        const float* sh = &out_l[n_loc * 40];
        float* fp = feats + (size_t)(gn0 + n_loc) * FEAT_DIM + h * HSEG;
        const float* R = Rl[n_loc];
        const float* tv = tl[n_loc];
        if (j < 16) {
            fp[j] = sh[j];
        } else if (j < 40) {
            const int jj = j - 16, p = jj / 3, i = jj % 3;
            float val = 0.f;
#pragma unroll
            for (int q = 0; q < 3; ++q) val += R[q * 3 + i] * (sh[16 + p * 3 + q] - tv[q]);
            fp[16 + jj] = val;
        } else {
            const int p = j - 40;
            float s2 = 0.f;
#pragma unroll
            for (int i = 0; i < 3; ++i) {
                float val = 0.f;
#pragma unroll
                for (int q = 0; q < 3; ++q) val += R[q * 3 + i] * (sh[16 + p * 3 + q] - tv[q]);
                s2 += val * val;
            }
            fp[40 + p] = sqrtf(s2);
        }
    }
}

// ---------------------------------------------------------------------------
// K5: pair_feat = attn^T @ z[n]  -> feats[..., 48:176]
// 4 waves own m-quarters (4x MLP on z stream); 12 heads x 2ch per thread;
// slab merge in LDS.
// ---------------------------------------------------------------------------
__global__ __launch_bounds__(256) void k_pairfeat(
    const float* __restrict__ attn,
    const float* __restrict__ z,
    float* __restrict__ feats)
{
    __shared__ float a_l[HN * NTOK];    // 24 KB
    __shared__ float out_l[HN * CZ];    // 6 KB
    const int n = blockIdx.x, t = threadIdx.x;
    for (int i = t; i < HN * NTOK; i += 256) a_l[i] = attn[(size_t)n * HN * NTOK + i];
    __syncthreads();

    const int slab = t >> 6, lane = t & 63;
    const int c2 = lane * 2;
    float acc[HN][2];
#pragma unroll
    for (int h = 0; h < HN; ++h) { acc[h][0] = 0.f; acc[h][1] = 0.f; }

    const float* zp = z + (size_t)n * NTOK * CZ + (size_t)slab * 128 * CZ + c2;
    const float* ap = a_l + slab * 128;
#pragma unroll 4
    for (int m = 0; m < 128; ++m) {
        float2 zv = *(const float2*)(zp + (size_t)m * CZ);
#pragma unroll
        for (int h = 0; h < HN; ++h) {
            float a = ap[h * NTOK + m];
            acc[h][0] += a * zv.x;
            acc[h][1] += a * zv.y;
        }
    }
    // merge 4 slabs
    for (int s = 0; s < 4; ++s) {
        __syncthreads();
        if (slab == s) {
#pragma unroll
            for (int h = 0; h < HN; ++h) {
                float* p = &out_l[h * CZ + c2];
                if (s == 0) { p[0] = acc[h][0]; p[1] = acc[h][1]; }
                else        { p[0] += acc[h][0]; p[1] += acc[h][1]; }
            }
        }
    }
    __syncthreads();
    for (int i = t; i < HN * CZ; i += 256) {
        const int h = i >> 7, c = i & 127;
        feats[(size_t)n * FEAT_DIM + h * HSEG + 48 + c] = out_l[i];
    }
}

// ---------------------------------------------------------------------------
// K6: out = feats @ Wout + bout  (f32, tiled K-split GEMM, atomic epilogue)
// ---------------------------------------------------------------------------
#define KT 16
__global__ __launch_bounds__(256) void k_outproj(
    const float* __restrict__ feats,
    const float* __restrict__ Wout,
    const float* __restrict__ bout,
    float* __restrict__ out)
{
    __shared__ float As[KT][64];   // As[k][row]
    __shared__ float Bs[KT][64];   // Bs[k][col]
    const int t  = threadIdx.x;
    const int n0 = blockIdx.x * 64;
    const int j0 = blockIdx.y * 64;
    const int k0 = blockIdx.z * HSEG;

    const int arow = t >> 2, akq = (t & 3) * 4;      // A: row, k-quad
    const int bkk  = t >> 4, bjq = (t & 15) * 4;     // B: k, col-quad
    const int tr   = t >> 4, tc  = t & 15;           // C: 4x4 tile coords

    float acc[4][4] = {{0.f}};
    for (int s = 0; s < 11; ++s) {
        const int ks = k0 + s * KT;
        float4 a4 = *(const float4*)&feats[(size_t)(n0 + arow) * FEAT_DIM + ks + akq];
        float4 b4 = *(const float4*)&Wout[(size_t)(ks + bkk) * 384 + j0 + bjq];
        __syncthreads();   // previous step's LDS reads complete
        As[akq + 0][arow] = a4.x;
        As[akq + 1][arow] = a4.y;
        As[akq + 2][arow] = a4.z;
        As[akq + 3][arow] = a4.w;
        *(float4*)&Bs[bkk][bjq] = b4;
        __syncthreads();
#pragma unroll
        for (int kk = 0; kk < KT; ++kk) {
            float4 av = *(const float4*)&As[kk][tr * 4];
            float4 bv = *(const float4*)&Bs[kk][tc * 4];
            acc[0][0] += av.x * bv.x; acc[0][1] += av.x * bv.y;
            acc[0][2] += av.x * bv.z; acc[0][3] += av.x * bv.w;
            acc[1][0] += av.y * bv.x; acc[1][1] += av.y * bv.y;
            acc[1][2] += av.y * bv.z; acc[1][3] += av.y * bv.w;
            acc[2][0] += av.z * bv.x; acc[2][1] += av.z * bv.y;
            acc[2][2] += av.z * bv.z; acc[2][3] += av.z * bv.w;
            acc[3][0] += av.w * bv.x; acc[3][1] += av.w * bv.y;
            acc[3][2] += av.w * bv.z; acc[3][3] += av.w * bv.w;
        }
    }

    const bool addb = (blockIdx.z == 0);
#pragma unroll
    for (int i = 0; i < 4; ++i) {
        const int row = n0 + tr * 4 + i;
#pragma unroll
        for (int jj = 0; jj < 4; ++jj) {
            const int col = j0 + tc * 4 + jj;
            float v = acc[i][jj];
            if (addb) v += bout[col];
            atomicAdd(&out[(size_t)row * 384 + col], v);
        }
    }
}

// ---------------------------------------------------------------------------
extern "C" void kernel_launch(void* const* d_in, const int* in_sizes, int n_in,
                              void* d_out, int out_size, void* d_ws, size_t ws_size,
                              hipStream_t stream) {
    const float* s     = (const float*)d_in[0];
    const float* z     = (const float*)d_in[1];
    const float* trans = (const float*)d_in[2];
    const float* rot   = (const float*)d_in[3];
    const float* Wq    = (const float*)d_in[4];
    const float* bq    = (const float*)d_in[5];
    const float* Wk    = (const float*)d_in[6];
    const float* bk    = (const float*)d_in[7];
    const float* Wv    = (const float*)d_in[8];
    const float* bv    = (const float*)d_in[9];
    const float* Wqp   = (const float*)d_in[10];
    const float* bqp   = (const float*)d_in[11];
    const float* Wkp   = (const float*)d_in[12];
    const float* bkp   = (const float*)d_in[13];
    const float* Wvp   = (const float*)d_in[14];
    const float* bvp   = (const float*)d_in[15];
    const float* Wb    = (const float*)d_in[16];
    const float* bb    = (const float*)d_in[17];
    const float* emb   = (const float*)d_in[18];
    const float* slog  = (const float*)d_in[19];
    const float* hw    = (const float*)d_in[20];
    const float* Wout  = (const float*)d_in[21];
    const float* bout  = (const float*)d_in[22];

    float* W = (float*)d_ws;
    float* qs     = W;                    // 512*192
    float* ksT    = qs + 98304;           // 192*512 (transposed)
    float* vs     = ksT + 98304;          // 512*192
    float* qg     = vs + 98304;           // 512*144
    float* kgT    = qg + 73728;           // 144*512 (transposed)
    float* vg     = kgT + 73728;          // 512*288
    float* transT = vg + 147456;          // 3*512
    float* bias   = transT + 1536;        // 512*12*512 (reused as attn)
    float* feats  = bias + 3145728;       // 512*2112
    float* raw_g  = feats + 1081344;      // 512*576
    // total: ~5.11M floats = 20.5 MB

    k_proj<<<dim3(32, 18), 256, 0, stream>>>(s, Wq, bq, Wk, bk, Wv, bv,
                                             Wqp, bqp, Wkp, bkp, Wvp, bvp,
                                             qs, ksT, vs, raw_g);
    k_frame<<<1158, 256, 0, stream>>>(raw_g, trans, rot, qg, kgT, vg, transT);
    k_bias<<<4096, 256, 0, stream>>>(z, Wb, bb, bias);
    k_attn<<<dim3(512, 12), 256, 0, stream>>>(qs, ksT, qg, kgT, trans, transT,
                                              emb, slog, hw, bias);
    k_outmm<<<dim3(16, 12), 256, 0, stream>>>(bias, vs, vg, trans, rot, feats);
    k_pairfeat<<<512, 256, 0, stream>>>(bias, z, feats);
    hipMemsetAsync(d_out, 0, (size_t)NTOK * 384 * sizeof(float), stream);
    k_outproj<<<dim3(8, 6, 12), 256, 0, stream>>>(feats, Wout, bout, (float*)d_out);
}